// Round 10
// baseline (275.685 us; speedup 1.0000x reference)
//
#include <hip/hip_runtime.h>
#include <hip/hip_bf16.h>
#include <cstdint>
#include <cstddef>

#define DMODEL 1024
#define DINNER 2048
#define NSTATE 16
#define DTRANK 64
#define BATCH 2
#define SEQ 1024
#define ROWS (BATCH*SEQ)   // 2048 token rows
#define NCHUNK 16
#define CLEN (SEQ/NCHUNK)  // 64
#define KSPLIT 16          // split-K ways for x_proj GEMM

typedef __attribute__((ext_vector_type(8))) short short8;
typedef __attribute__((ext_vector_type(4))) short short4v;
typedef __attribute__((ext_vector_type(4))) float f32x4;

__device__ __forceinline__ float bf2f(__hip_bfloat16 h){ return __bfloat162float(h); }
__device__ __forceinline__ float sigmoidf_(float x){ return 1.0f/(1.0f + __expf(-x)); }
__device__ __forceinline__ unsigned short f2bfbits(float v){
  __hip_bfloat16 h = __float2bfloat16(v);
  return *(unsigned short*)&h;
}
__device__ __forceinline__ float bfbits2f(unsigned short u){
  unsigned int x = ((unsigned int)u) << 16;
  return *(float*)&x;
}

__device__ __forceinline__ void gld16(const void* g, void* l){
  __builtin_amdgcn_global_load_lds((const __attribute__((address_space(1))) void*)g,
                                   (__attribute__((address_space(3))) void*)l, 16, 0, 0);
}

// ---------------------------------------------------------------------------
// dtype sniffer — separate tiny kernel (R8 lesson: inlining it per-thread in
// the convert kernel cost +30us of VMEM issue).
// ---------------------------------------------------------------------------
__global__ void sniff_k(const unsigned short* __restrict__ xu, int* __restrict__ flag)
{
  int t = threadIdx.x;           // 64 threads
  int cnt = 0;
  for (int i = t; i < 1024; i += 64) {
    unsigned short u = xu[i];
    int e = (u >> 7) & 0xFF;
    if (e >= 0x70 && e <= 0x86) cnt++;
  }
  for (int o = 32; o; o >>= 1) cnt += __shfl_down(cnt, o);
  if (t == 0) *flag = (cnt >= 768) ? 0 : 1;
}

// ---------------------------------------------------------------------------
// Fused canonicalizer, x4 vectorized (R9 ran scalar at 68% VALUBusy — issue
// bound). Each thread converts 4 consecutive elements (all segment bounds
// are divisible by 4). + d_out zero-init in the first 2048 blocks.
// ---------------------------------------------------------------------------
struct CvtArgs {
  const void *s0,*s1,*s2,*s3,*s4,*s5,*s6,*s7,*s8,*s9;
  __hip_bfloat16 *xB,*inpB,*xprojB,*dtprojB,*outpB;
  float *cwF,*cbF,*dtbF,*alF,*DF;
  float *outZ;
  const int* flag;
};
#define CVT_C1 2097152
#define CVT_C2 6291456
#define CVT_C3 6299648
#define CVT_C4 6301696
#define CVT_C5 6498304
#define CVT_C6 6629376
#define CVT_C7 6631424
#define CVT_C8 6664192
#define CVT_C9 6666240
#define CVT_TOT 8763392
#define CVT_BLOCKS (CVT_TOT/4/256)   // 8558

__device__ __forceinline__ void cvt_read4(const void* s, int j, int fl, float v[4]){
  if (fl) {
    f32x4 t = ((const f32x4*)s)[j>>2];
    v[0]=t.x; v[1]=t.y; v[2]=t.z; v[3]=t.w;
  } else {
    short4v t = *(const short4v*)((const __hip_bfloat16*)s + j);
    v[0]=bfbits2f((unsigned short)t.x); v[1]=bfbits2f((unsigned short)t.y);
    v[2]=bfbits2f((unsigned short)t.z); v[3]=bfbits2f((unsigned short)t.w);
  }
}
__device__ __forceinline__ void cvt_wB(__hip_bfloat16* d, int j, const float v[4]){
  short4v o;
  o.x=(short)f2bfbits(v[0]); o.y=(short)f2bfbits(v[1]);
  o.z=(short)f2bfbits(v[2]); o.w=(short)f2bfbits(v[3]);
  *(short4v*)(d + j) = o;
}
__device__ __forceinline__ void cvt_wF(float* d, int j, const float v[4]){
  f32x4 o = { v[0], v[1], v[2], v[3] };
  *(f32x4*)(d + j) = o;
}

__global__ __launch_bounds__(256)
void convert_all_k(CvtArgs a)
{
  int i4 = blockIdx.x * 256 + threadIdx.x;
  const int fl = *a.flag;

  // zero d_out (2M floats) with the first 2048 blocks
  if (blockIdx.x < 2048) {
    f32x4 z = {0.f, 0.f, 0.f, 0.f};
    ((f32x4*)a.outZ)[i4] = z;
  }

  int i = i4 * 4;
  if (i >= CVT_TOT) return;
  float v[4];
  if (i < CVT_C1)      { cvt_read4(a.s0, i, fl, v);        cvt_wB(a.xB, i, v); }
  else if (i < CVT_C2) { cvt_read4(a.s1, i-CVT_C1, fl, v); cvt_wB(a.inpB, i-CVT_C1, v); }
  else if (i < CVT_C3) { cvt_read4(a.s2, i-CVT_C2, fl, v); cvt_wF(a.cwF, i-CVT_C2, v); }
  else if (i < CVT_C4) { cvt_read4(a.s3, i-CVT_C3, fl, v); cvt_wF(a.cbF, i-CVT_C3, v); }
  else if (i < CVT_C5) { cvt_read4(a.s4, i-CVT_C4, fl, v); cvt_wB(a.xprojB, i-CVT_C4, v); }
  else if (i < CVT_C6) { cvt_read4(a.s5, i-CVT_C5, fl, v); cvt_wB(a.dtprojB, i-CVT_C5, v); }
  else if (i < CVT_C7) { cvt_read4(a.s6, i-CVT_C6, fl, v); cvt_wF(a.dtbF, i-CVT_C6, v); }
  else if (i < CVT_C8) { cvt_read4(a.s7, i-CVT_C7, fl, v); cvt_wF(a.alF, i-CVT_C7, v); }
  else if (i < CVT_C9) { cvt_read4(a.s8, i-CVT_C8, fl, v); cvt_wF(a.DF, i-CVT_C8, v); }
  else                 { cvt_read4(a.s9, i-CVT_C9, fl, v); cvt_wB(a.outpB, i-CVT_C9, v); }
}

// ---------------------------------------------------------------------------
// NT GEMM (validated R8/R9): BK=64, XOR-swizzled LDS staging.
// EPI: 3 = softplus(acc + biasF[col]) -> f32 (delta)
//      4 = in_proj split: col<2048 -> bf16 xi (outH); col>=2048 -> silu -> bf16 outH2
//      5 = split-K partial: f32 -> outF + z*ROWS*96, cols<96 (x_proj)
//      6 = split-K atomic: unsafeAtomicAdd into outF [row,DMODEL] (out_proj)
// ---------------------------------------------------------------------------
template<int EPI>
__global__ __launch_bounds__(256)
void gemm64(const __hip_bfloat16* __restrict__ A,
            const __hip_bfloat16* __restrict__ W,
            int M, int N, int K, int kchunk,
            float* __restrict__ outF,
            __hip_bfloat16* __restrict__ outH,
            __hip_bfloat16* __restrict__ outH2,
            const float* __restrict__ biasF)
{
  __shared__ alignas(16) __hip_bfloat16 As[128*64];   // 16 KB
  __shared__ alignas(16) __hip_bfloat16 Ws[128*64];   // 16 KB
  const int tid  = threadIdx.x;
  const int lane = tid & 63;
  const int wave = tid >> 6;
  const int wm = wave & 1, wn = wave >> 1;
  const int row0 = blockIdx.y * 128;
  const int col0 = blockIdx.x * 128;

  f32x4 acc[4][4] = {};

  int kbeg = 0, kend = K;
  if (EPI == 5 || EPI == 6) { kbeg = blockIdx.z * kchunk; kend = kbeg + kchunk; }

  const int r16 = lane & 15, q = lane >> 4;
  const int sx0 = ((q ^ (r16 & 7)) * 16);

  for (int k0 = kbeg; k0 < kend; k0 += 64) {
#pragma unroll
    for (int j = 0; j < 4; ++j) {             // A tile
      int e = tid + j*256;
      int r = e >> 3, g = e & 7;
      int kc = ((g ^ (r & 7)) << 3);
      gld16(A + (size_t)(row0 + r) * K + k0 + kc, (char*)As + (size_t)e*16);
    }
#pragma unroll
    for (int j = 0; j < 4; ++j) {             // W tile
      int e = tid + j*256;
      int r = e >> 3, g = e & 7;
      int kc = ((g ^ (r & 7)) << 3);
      int rw = col0 + r; if (EPI == 5 && rw > N-1) rw = N-1;
      gld16(W + (size_t)rw * K + k0 + kc, (char*)Ws + (size_t)e*16);
    }
    __syncthreads();

    const char* Ab = (const char*)As + ((wm*64 + r16) * 128);
    const char* Wb = (const char*)Ws + ((wn*64 + r16) * 128);
#pragma unroll
    for (int ksub = 0; ksub < 2; ++ksub) {
      const int sx = sx0 ^ (ksub * 64);
      short8 af[4], wf[4];
#pragma unroll
      for (int i = 0; i < 4; ++i) af[i] = *(const short8*)(Ab + i*16*128 + sx);
#pragma unroll
      for (int i = 0; i < 4; ++i) wf[i] = *(const short8*)(Wb + i*16*128 + sx);
#pragma unroll
      for (int mt = 0; mt < 4; ++mt)
#pragma unroll
        for (int nt = 0; nt < 4; ++nt)
          acc[mt][nt] = __builtin_amdgcn_mfma_f32_16x16x32_bf16(af[mt], wf[nt], acc[mt][nt], 0, 0, 0);
    }
    __syncthreads();
  }

  // C/D layout (verified m89/m91): col = lane&15, row = (lane>>4)*4 + r
  const int mbase = row0 + wm*64 + (q * 4);
  const int nbase = col0 + wn*64 + r16;

  float bv[4];
  if (EPI == 3) {
#pragma unroll
    for (int nt = 0; nt < 4; ++nt) bv[nt] = biasF[nbase + nt*16];
  }

#pragma unroll
  for (int mt = 0; mt < 4; ++mt) {
#pragma unroll
    for (int nt = 0; nt < 4; ++nt) {
#pragma unroll
      for (int r = 0; r < 4; ++r) {
        int row = mbase + mt*16 + r;
        int col = nbase + nt*16;
        float v = acc[mt][nt][r];
        if (EPI == 3) {
          v += bv[nt];
          float sp = fmaxf(v, 0.0f) + __logf(1.0f + __expf(-fabsf(v)));
          outF[(size_t)row * DINNER + col] = sp;
        } else if (EPI == 4) {
          if (col < DINNER) {
            outH[(size_t)row * DINNER + col] = __float2bfloat16(v);
          } else {
            outH2[(size_t)row * DINNER + (col - DINNER)] = __float2bfloat16(v * sigmoidf_(v));
          }
        } else if (EPI == 5) {
          if (col < 96)
            outF[(size_t)blockIdx.z * (ROWS*96) + (size_t)row * 96 + col] = v;
        } else if (EPI == 6) {
          unsafeAtomicAdd(&outF[(size_t)row * DMODEL + col], v);
        }
      }
    }
  }
}

// ---------------------------------------------------------------------------
__global__ __launch_bounds__(256)
void reduce_xdbl_k(const float* __restrict__ part, float* __restrict__ xdbl,
                   __hip_bfloat16* __restrict__ dtH)
{
  int i = blockIdx.x * 256 + threadIdx.x;
  if (i >= ROWS*96) return;
  float s = 0.f;
#pragma unroll
  for (int kc = 0; kc < KSPLIT; ++kc) s += part[(size_t)kc*ROWS*96 + i];
  xdbl[i] = s;
  int row = i / 96, col = i - row*96;
  if (col < 64) dtH[(size_t)row*64 + col] = __float2bfloat16(s);
}

// ---------------------------------------------------------------------------
__global__ __launch_bounds__(256)
void conv_silu_k(const __hip_bfloat16* __restrict__ xi,
                 const float* __restrict__ cw,
                 const float* __restrict__ cb,
                 __hip_bfloat16* __restrict__ xcH)
{
  int idx = blockIdx.x * 256 + threadIdx.x;
  if (idx >= ROWS * DINNER) return;
  int d  = idx & (DINNER - 1);
  int t  = (idx >> 11) & (SEQ - 1);
  int bt = idx >> 11;
  float acc = cb[d];
#pragma unroll
  for (int i = 0; i < 4; ++i) {
    int tt = t - 3 + i;
    if (tt >= 0) acc += cw[d*4 + i] * bf2f(xi[(size_t)(bt - 3 + i) * DINNER + d]);
  }
  float y = acc * sigmoidf_(acc);
  xcH[idx] = __float2bfloat16(y);
}

// ---------------------------------------------------------------------------
// Chunked selective scan (lane layout validated R7): 4 lanes/channel,
// 4 states/lane, B/C staged per block in LDS, 2 shfl_xor reduce.
// GSTEP 8->16 this round: both passes are latency-bound (VALU ~42%);
// deeper prefetch doubles outstanding loads per wave.
// ---------------------------------------------------------------------------
#define GSTEP 16

__global__ __launch_bounds__(256)
void stats_k(const float* __restrict__ delta,
             const __hip_bfloat16* __restrict__ xcH,
             const float* __restrict__ xdbl,
             const float* __restrict__ alF,
             float* __restrict__ Hc, float* __restrict__ Sd)
{
  __shared__ alignas(16) float Bs[CLEN*16];     // 4 KB
  const int bid  = blockIdx.x;                  // b*512 + c*32 + cg
  const int b    = bid >> 9;
  const int c    = (bid >> 5) & (NCHUNK-1);
  const int cg   = bid & 31;
  const int tid  = threadIdx.x;
  const int lane = tid & 63;
  const int wave = tid >> 6;
  const int sub  = lane & 3;
  const int ch   = (cg << 6) + (wave << 4) + (lane >> 2);

  const size_t rb = (size_t)b * SEQ + (size_t)c * CLEN;

  for (int i = tid; i < CLEN*16; i += 256) {
    int t = i >> 4, j = i & 15;
    Bs[i] = xdbl[(rb + t)*96 + 64 + j];
  }
  __syncthreads();

  float negA[4];
#pragma unroll
  for (int j = 0; j < 4; ++j) negA[j] = -__expf(alF[ch*NSTATE + sub*4 + j]);

  const float*          dp = delta + rb * DINNER + ch;
  const __hip_bfloat16* xp = xcH   + rb * DINNER + ch;

  float h0=0.f,h1=0.f,h2=0.f,h3=0.f, sd=0.f;
  float d0[GSTEP], x0[GSTEP], d1[GSTEP], x1[GSTEP];

#define PF1(D_,X_,T0) \
  _Pragma("unroll") \
  for (int u = 0; u < GSTEP; ++u) { \
    D_[u] = dp[(size_t)((T0)+u) * DINNER]; \
    X_[u] = bf2f(xp[(size_t)((T0)+u) * DINNER]); \
  }
#define ST1(D_,X_,T0) \
  _Pragma("unroll") \
  for (int u = 0; u < GSTEP; ++u) { \
    float d_ = D_[u]; \
    sd += d_; \
    float du = d_ * X_[u]; \
    f32x4 B4 = *(const f32x4*)&Bs[((T0)+u)*16 + sub*4]; \
    h0 = __expf(d_*negA[0])*h0 + du*B4.x; \
    h1 = __expf(d_*negA[1])*h1 + du*B4.y; \
    h2 = __expf(d_*negA[2])*h2 + du*B4.z; \
    h3 = __expf(d_*negA[3])*h3 + du*B4.w; \
  }

  PF1(d0, x0, 0)
  for (int t0 = 0; t0 < CLEN; t0 += 2*GSTEP) {
    PF1(d1, x1, t0 + GSTEP)
    ST1(d0, x0, t0)
    if (t0 + 2*GSTEP < CLEN) { PF1(d0, x0, t0 + 2*GSTEP) }
    ST1(d1, x1, t0 + GSTEP)
  }
#undef PF1
#undef ST1

  const size_t bc = (size_t)(b*NCHUNK + c);
  f32x4 hv = { h0, h1, h2, h3 };
  *(f32x4*)&Hc[(bc*DINNER + ch)*NSTATE + sub*4] = hv;
  if (sub == 0) Sd[bc*DINNER + ch] = sd;
}

__global__ __launch_bounds__(256)
void carry_k(const float* __restrict__ Hc, const float* __restrict__ Sd,
             const float* __restrict__ alF, float* __restrict__ hin)
{
  int i = blockIdx.x * 256 + threadIdx.x;       // BATCH*DINNER*NSTATE = 65536
  int n  = i & (NSTATE-1);
  int ch = (i >> 4) & (DINNER-1);
  int b  = i >> 15;
  float negA = -__expf(alF[ch * NSTATE + n]);
  float h = 0.f;
#pragma unroll
  for (int c = 0; c < NCHUNK; ++c) {
    size_t bc = (size_t)(b*NCHUNK + c);
    hin[(bc*DINNER + ch)*NSTATE + n] = h;
    float P = __expf(negA * Sd[bc*DINNER + ch]);
    h = P * h + Hc[(bc*DINNER + ch)*NSTATE + n];
  }
}

__global__ __launch_bounds__(256)
void emit_k(const float* __restrict__ delta,
            const __hip_bfloat16* __restrict__ xcH,
            const float* __restrict__ xdbl,
            const __hip_bfloat16* __restrict__ zsH,
            const float* __restrict__ alF,
            const float* __restrict__ DF,
            const float* __restrict__ hin,
            __hip_bfloat16* __restrict__ yH)
{
  __shared__ alignas(16) float BCs[CLEN*32];    // 8 KB
  const int bid  = blockIdx.x;
  const int b    = bid >> 9;
  const int c    = (bid >> 5) & (NCHUNK-1);
  const int cg   = bid & 31;
  const int tid  = threadIdx.x;
  const int lane = tid & 63;
  const int wave = tid >> 6;
  const int sub  = lane & 3;
  const int ch   = (cg << 6) + (wave << 4) + (lane >> 2);

  const size_t rb = (size_t)b * SEQ + (size_t)c * CLEN;

  for (int i = tid; i < CLEN*32; i += 256) {
    int t = i >> 5, j = i & 31;
    BCs[i] = xdbl[(rb + t)*96 + 64 + j];
  }
  __syncthreads();

  float negA[4];
#pragma unroll
  for (int j = 0; j < 4; ++j) negA[j] = -__expf(alF[ch*NSTATE + sub*4 + j]);
  const float Dch = DF[ch];

  const float*          dp = delta + rb * DINNER + ch;
  const __hip_bfloat16* xp = xcH   + rb * DINNER + ch;
  const __hip_bfloat16* zp = zsH   + rb * DINNER + ch;
  __hip_bfloat16*       yp = yH    + rb * DINNER + ch;

  f32x4 hv = *(const f32x4*)&hin[((size_t)(b*NCHUNK + c)*DINNER + ch)*NSTATE + sub*4];
  float h0=hv.x, h1=hv.y, h2=hv.z, h3=hv.w;

  float d0[GSTEP], x0[GSTEP], z0[GSTEP], d1[GSTEP], x1[GSTEP], z1[GSTEP];

#define PF(D_,X_,Z_,T0) \
  _Pragma("unroll") \
  for (int u = 0; u < GSTEP; ++u) { \
    D_[u] = dp[(size_t)((T0)+u) * DINNER]; \
    X_[u] = bf2f(xp[(size_t)((T0)+u) * DINNER]); \
    Z_[u] = bf2f(zp[(size_t)((T0)+u) * DINNER]); \
  }
#define STEPS(D_,X_,Z_,T0) \
  _Pragma("unroll") \
  for (int u = 0; u < GSTEP; ++u) { \
    float d_ = D_[u]; \
    float du = d_ * X_[u]; \
    f32x4 B4 = *(const f32x4*)&BCs[((T0)+u)*32 + sub*4]; \
    f32x4 C4 = *(const f32x4*)&BCs[((T0)+u)*32 + 16 + sub*4]; \
    h0 = __expf(d_*negA[0])*h0 + du*B4.x; \
    h1 = __expf(d_*negA[1])*h1 + du*B4.y; \
    h2 = __expf(d_*negA[2])*h2 + du*B4.z; \
    h3 = __expf(d_*negA[3])*h3 + du*B4.w; \
    float p = h0*C4.x + h1*C4.y + h2*C4.z + h3*C4.w; \
    p += __shfl_xor(p, 1); \
    p += __shfl_xor(p, 2); \
    if (sub == 0) { \
      float y = (p + X_[u] * Dch) * Z_[u]; \
      yp[(size_t)((T0)+u) * DINNER] = __float2bfloat16(y); \
    } \
  }

  PF(d0, x0, z0, 0)
  for (int t0 = 0; t0 < CLEN; t0 += 2*GSTEP) {
    PF(d1, x1, z1, t0 + GSTEP)
    STEPS(d0, x0, z0, t0)
    if (t0 + 2*GSTEP < CLEN) { PF(d0, x0, z0, t0 + 2*GSTEP) }
    STEPS(d1, x1, z1, t0 + GSTEP)
  }
#undef PF
#undef STEPS
}

// ---------------------------------------------------------------------------
extern "C" void kernel_launch(void* const* d_in, const int* in_sizes, int n_in,
                              void* d_out, int out_size, void* d_ws, size_t ws_size,
                              hipStream_t stream)
{
  float* out = (float*)d_out;   // reference output dtype: float32
  char* ws = (char*)d_ws;
  const size_t MB = 1024*1024;

  // workspace layout (68 MB, liveness-aliased)
  int*            flag    = (int*)            (ws);
  float*          cwF     = (float*)          (ws + 1024);
  float*          cbF     = (float*)          (ws + 40*1024);
  float*          dtbF    = (float*)          (ws + 56*1024);
  float*          alF     = (float*)          (ws + 72*1024);
  float*          DF      = (float*)          (ws + 208*1024);
  float*          Sd      = (float*)          (ws + 256*1024);      // 256 KB
  __hip_bfloat16* xB      = (__hip_bfloat16*) (ws + 1*MB);          // 4 MB  (dead after G1)
  __hip_bfloat16* inpB    = (__hip_bfloat16*) (ws + 5*MB);          // 8 MB  (dead after G1)
  __hip_bfloat16* xiB     = (__hip_bfloat16*) (ws + 13*MB);         // 8 MB  (dead after conv)
  float*          part    = (float*)          (ws + 1*MB);          // 12 MB aliases xB/inpB
  float*          dlt     = (float*)          (ws + 1*MB);          // 16 MB aliases part/xiB[:4MB]
  __hip_bfloat16* xprojB  = (__hip_bfloat16*) (ws + 21*MB);
  __hip_bfloat16* dtprojB = (__hip_bfloat16*) (ws + 21*MB + 512*1024);
  __hip_bfloat16* outpB   = (__hip_bfloat16*) (ws + 22*MB);         // 4 MB
  __hip_bfloat16* zsH     = (__hip_bfloat16*) (ws + 26*MB);         // 8 MB (bf16 silu(z))
  __hip_bfloat16* xcH     = (__hip_bfloat16*) (ws + 42*MB);         // 8 MB
  float*          xdbl    = (float*)          (ws + 50*MB);         // 768 KB
  __hip_bfloat16* dtH     = (__hip_bfloat16*) (ws + 51*MB);         // 256 KB
  __hip_bfloat16* yH      = (__hip_bfloat16*) (ws + 52*MB);         // 8 MB
  float*          Hc      = (float*)          (ws + 60*MB);         // 4 MB
  float*          hin     = (float*)          (ws + 64*MB);         // 4 MB -> top 68 MB

  dim3 blk(256);

  // 0) sniff (1 tiny block) + vectorized canonicalize (+ d_out zero-init)
  sniff_k<<<1, 64, 0, stream>>>((const unsigned short*)d_in[0], flag);
  CvtArgs ca = { d_in[0], d_in[1], d_in[2], d_in[3], d_in[4],
                 d_in[5], d_in[6], d_in[7], d_in[8], d_in[9],
                 xB, inpB, xprojB, dtprojB, outpB,
                 cwF, cbF, dtbF, alF, DF, out, flag };
  convert_all_k<<<CVT_BLOCKS, blk, 0, stream>>>(ca);

  // 1) in_proj (2048 x 4096 x 1024): split -> xi bf16, silu(z) bf16
  gemm64<4><<<dim3(4096/128, ROWS/128), blk, 0, stream>>>(
      xB, inpB, ROWS, 2*DINNER, DMODEL, 0, nullptr, xiB, zsH, nullptr);

  // 2) xc = silu(depthwise_conv(xi) + b)
  conv_silu_k<<<(ROWS*DINNER)/256, blk, 0, stream>>>(xiB, cwF, cbF, xcH);

  // 3) x_dbl (2048 x 96 x 2048): 16-way split-K + reduce
  gemm64<5><<<dim3(1, ROWS/128, KSPLIT), blk, 0, stream>>>(
      xcH, xprojB, ROWS, 96, DINNER, DINNER/KSPLIT, part, nullptr, nullptr, nullptr);
  reduce_xdbl_k<<<(ROWS*96+255)/256, blk, 0, stream>>>(part, xdbl, dtH);

  // 4) delta = softplus(dt @ dt_proj^T + dt_b) (2048 x 2048 x 64): single K-iter
  gemm64<3><<<dim3(DINNER/128, ROWS/128), blk, 0, stream>>>(
      dtH, dtprojB, ROWS, DINNER, DTRANK, 0, dlt, nullptr, nullptr, dtbF);

  // 5) chunked selective scan + fused combine -> bf16 yH
  stats_k<<<BATCH*NCHUNK*32, blk, 0, stream>>>(dlt, xcH, xdbl, alF, Hc, Sd);
  carry_k<<<(BATCH*DINNER*NSTATE)/256, blk, 0, stream>>>(Hc, Sd, alF, hin);
  emit_k<<<BATCH*NCHUNK*32, blk, 0, stream>>>(dlt, xcH, xdbl, zsH, alF, DF, hin, yH);

  // 6) out_proj (2048 x 1024 x 2048): split-K=4, atomic accumulate into d_out
  gemm64<6><<<dim3(DMODEL/128, ROWS/128, 4), blk, 0, stream>>>(
      yH, outpB, ROWS, DMODEL, DINNER, DINNER/4, out, nullptr, nullptr, nullptr);
}

// Round 11
// 250.669 us; speedup vs baseline: 1.0998x; 1.0998x over previous
//
#include <hip/hip_runtime.h>
#include <hip/hip_bf16.h>
#include <cstdint>
#include <cstddef>

#define DMODEL 1024
#define DINNER 2048
#define NSTATE 16
#define DTRANK 64
#define BATCH 2
#define SEQ 1024
#define ROWS (BATCH*SEQ)   // 2048 token rows
#define NCHUNK 16
#define CLEN (SEQ/NCHUNK)  // 64
#define KSPLIT 16          // split-K ways for x_proj GEMM

typedef __attribute__((ext_vector_type(8))) short short8;
typedef __attribute__((ext_vector_type(4))) short short4v;
typedef __attribute__((ext_vector_type(4))) float f32x4;

__device__ __forceinline__ float bf2f(__hip_bfloat16 h){ return __bfloat162float(h); }
__device__ __forceinline__ float sigmoidf_(float x){ return 1.0f/(1.0f + __expf(-x)); }
__device__ __forceinline__ unsigned short f2bfbits(float v){
  __hip_bfloat16 h = __float2bfloat16(v);
  return *(unsigned short*)&h;
}
__device__ __forceinline__ float bfbits2f(unsigned short u){
  unsigned int x = ((unsigned int)u) << 16;
  return *(float*)&x;
}

__device__ __forceinline__ void gld16(const void* g, void* l){
  __builtin_amdgcn_global_load_lds((const __attribute__((address_space(1))) void*)g,
                                   (__attribute__((address_space(3))) void*)l, 16, 0, 0);
}

// ---------------------------------------------------------------------------
// dtype sniffer — separate tiny kernel (R8 lesson: inlining per-thread in the
// convert kernel cost +30us of VMEM issue).
// ---------------------------------------------------------------------------
__global__ void sniff_k(const unsigned short* __restrict__ xu, int* __restrict__ flag)
{
  int t = threadIdx.x;           // 64 threads
  int cnt = 0;
  for (int i = t; i < 1024; i += 64) {
    unsigned short u = xu[i];
    int e = (u >> 7) & 0xFF;
    if (e >= 0x70 && e <= 0x86) cnt++;
  }
  for (int o = 32; o; o >>= 1) cnt += __shfl_down(cnt, o);
  if (t == 0) *flag = (cnt >= 768) ? 0 : 1;
}

// ---------------------------------------------------------------------------
// Fused canonicalizer, x4 vectorized (validated R10) + d_out zero-init.
// ---------------------------------------------------------------------------
struct CvtArgs {
  const void *s0,*s1,*s2,*s3,*s4,*s5,*s6,*s7,*s8,*s9;
  __hip_bfloat16 *xB,*inpB,*xprojB,*dtprojB,*outpB;
  float *cwF,*cbF,*dtbF,*alF,*DF;
  float *outZ;
  const int* flag;
};
#define CVT_C1 2097152
#define CVT_C2 6291456
#define CVT_C3 6299648
#define CVT_C4 6301696
#define CVT_C5 6498304
#define CVT_C6 6629376
#define CVT_C7 6631424
#define CVT_C8 6664192
#define CVT_C9 6666240
#define CVT_TOT 8763392
#define CVT_BLOCKS (CVT_TOT/4/256)   // 8558

__device__ __forceinline__ void cvt_read4(const void* s, int j, int fl, float v[4]){
  if (fl) {
    f32x4 t = ((const f32x4*)s)[j>>2];
    v[0]=t.x; v[1]=t.y; v[2]=t.z; v[3]=t.w;
  } else {
    short4v t = *(const short4v*)((const __hip_bfloat16*)s + j);
    v[0]=bfbits2f((unsigned short)t.x); v[1]=bfbits2f((unsigned short)t.y);
    v[2]=bfbits2f((unsigned short)t.z); v[3]=bfbits2f((unsigned short)t.w);
  }
}
__device__ __forceinline__ void cvt_wB(__hip_bfloat16* d, int j, const float v[4]){
  short4v o;
  o.x=(short)f2bfbits(v[0]); o.y=(short)f2bfbits(v[1]);
  o.z=(short)f2bfbits(v[2]); o.w=(short)f2bfbits(v[3]);
  *(short4v*)(d + j) = o;
}
__device__ __forceinline__ void cvt_wF(float* d, int j, const float v[4]){
  f32x4 o = { v[0], v[1], v[2], v[3] };
  *(f32x4*)(d + j) = o;
}

__global__ __launch_bounds__(256)
void convert_all_k(CvtArgs a)
{
  int i4 = blockIdx.x * 256 + threadIdx.x;
  const int fl = *a.flag;

  // zero d_out (2M floats) with the first 2048 blocks
  if (blockIdx.x < 2048) {
    f32x4 z = {0.f, 0.f, 0.f, 0.f};
    ((f32x4*)a.outZ)[i4] = z;
  }

  int i = i4 * 4;
  if (i >= CVT_TOT) return;
  float v[4];
  if (i < CVT_C1)      { cvt_read4(a.s0, i, fl, v);        cvt_wB(a.xB, i, v); }
  else if (i < CVT_C2) { cvt_read4(a.s1, i-CVT_C1, fl, v); cvt_wB(a.inpB, i-CVT_C1, v); }
  else if (i < CVT_C3) { cvt_read4(a.s2, i-CVT_C2, fl, v); cvt_wF(a.cwF, i-CVT_C2, v); }
  else if (i < CVT_C4) { cvt_read4(a.s3, i-CVT_C3, fl, v); cvt_wF(a.cbF, i-CVT_C3, v); }
  else if (i < CVT_C5) { cvt_read4(a.s4, i-CVT_C4, fl, v); cvt_wB(a.xprojB, i-CVT_C4, v); }
  else if (i < CVT_C6) { cvt_read4(a.s5, i-CVT_C5, fl, v); cvt_wB(a.dtprojB, i-CVT_C5, v); }
  else if (i < CVT_C7) { cvt_read4(a.s6, i-CVT_C6, fl, v); cvt_wF(a.dtbF, i-CVT_C6, v); }
  else if (i < CVT_C8) { cvt_read4(a.s7, i-CVT_C7, fl, v); cvt_wF(a.alF, i-CVT_C7, v); }
  else if (i < CVT_C9) { cvt_read4(a.s8, i-CVT_C8, fl, v); cvt_wF(a.DF, i-CVT_C8, v); }
  else                 { cvt_read4(a.s9, i-CVT_C9, fl, v); cvt_wB(a.outpB, i-CVT_C9, v); }
}

// ---------------------------------------------------------------------------
// NT GEMM (validated R8/R9): BK=64, XOR-swizzled LDS staging.
// EPI: 3 = softplus(acc + biasF[col]) -> f32 (delta)
//      4 = in_proj split: col<2048 -> bf16 xi (outH); col>=2048 -> silu -> bf16 outH2
//      5 = split-K partial: f32 -> outF + z*ROWS*96, cols<96 (x_proj)
//      6 = split-K atomic: unsafeAtomicAdd into outF [row,DMODEL] (out_proj)
// ---------------------------------------------------------------------------
template<int EPI>
__global__ __launch_bounds__(256)
void gemm64(const __hip_bfloat16* __restrict__ A,
            const __hip_bfloat16* __restrict__ W,
            int M, int N, int K, int kchunk,
            float* __restrict__ outF,
            __hip_bfloat16* __restrict__ outH,
            __hip_bfloat16* __restrict__ outH2,
            const float* __restrict__ biasF)
{
  __shared__ alignas(16) __hip_bfloat16 As[128*64];   // 16 KB
  __shared__ alignas(16) __hip_bfloat16 Ws[128*64];   // 16 KB
  const int tid  = threadIdx.x;
  const int lane = tid & 63;
  const int wave = tid >> 6;
  const int wm = wave & 1, wn = wave >> 1;
  const int row0 = blockIdx.y * 128;
  const int col0 = blockIdx.x * 128;

  f32x4 acc[4][4] = {};

  int kbeg = 0, kend = K;
  if (EPI == 5 || EPI == 6) { kbeg = blockIdx.z * kchunk; kend = kbeg + kchunk; }

  const int r16 = lane & 15, q = lane >> 4;
  const int sx0 = ((q ^ (r16 & 7)) * 16);

  for (int k0 = kbeg; k0 < kend; k0 += 64) {
#pragma unroll
    for (int j = 0; j < 4; ++j) {             // A tile
      int e = tid + j*256;
      int r = e >> 3, g = e & 7;
      int kc = ((g ^ (r & 7)) << 3);
      gld16(A + (size_t)(row0 + r) * K + k0 + kc, (char*)As + (size_t)e*16);
    }
#pragma unroll
    for (int j = 0; j < 4; ++j) {             // W tile
      int e = tid + j*256;
      int r = e >> 3, g = e & 7;
      int kc = ((g ^ (r & 7)) << 3);
      int rw = col0 + r; if (EPI == 5 && rw > N-1) rw = N-1;
      gld16(W + (size_t)rw * K + k0 + kc, (char*)Ws + (size_t)e*16);
    }
    __syncthreads();

    const char* Ab = (const char*)As + ((wm*64 + r16) * 128);
    const char* Wb = (const char*)Ws + ((wn*64 + r16) * 128);
#pragma unroll
    for (int ksub = 0; ksub < 2; ++ksub) {
      const int sx = sx0 ^ (ksub * 64);
      short8 af[4], wf[4];
#pragma unroll
      for (int i = 0; i < 4; ++i) af[i] = *(const short8*)(Ab + i*16*128 + sx);
#pragma unroll
      for (int i = 0; i < 4; ++i) wf[i] = *(const short8*)(Wb + i*16*128 + sx);
#pragma unroll
      for (int mt = 0; mt < 4; ++mt)
#pragma unroll
        for (int nt = 0; nt < 4; ++nt)
          acc[mt][nt] = __builtin_amdgcn_mfma_f32_16x16x32_bf16(af[mt], wf[nt], acc[mt][nt], 0, 0, 0);
    }
    __syncthreads();
  }

  // C/D layout (verified m89/m91): col = lane&15, row = (lane>>4)*4 + r
  const int mbase = row0 + wm*64 + (q * 4);
  const int nbase = col0 + wn*64 + r16;

  float bv[4];
  if (EPI == 3) {
#pragma unroll
    for (int nt = 0; nt < 4; ++nt) bv[nt] = biasF[nbase + nt*16];
  }

#pragma unroll
  for (int mt = 0; mt < 4; ++mt) {
#pragma unroll
    for (int nt = 0; nt < 4; ++nt) {
#pragma unroll
      for (int r = 0; r < 4; ++r) {
        int row = mbase + mt*16 + r;
        int col = nbase + nt*16;
        float v = acc[mt][nt][r];
        if (EPI == 3) {
          v += bv[nt];
          float sp = fmaxf(v, 0.0f) + __logf(1.0f + __expf(-fabsf(v)));
          outF[(size_t)row * DINNER + col] = sp;
        } else if (EPI == 4) {
          if (col < DINNER) {
            outH[(size_t)row * DINNER + col] = __float2bfloat16(v);
          } else {
            outH2[(size_t)row * DINNER + (col - DINNER)] = __float2bfloat16(v * sigmoidf_(v));
          }
        } else if (EPI == 5) {
          if (col < 96)
            outF[(size_t)blockIdx.z * (ROWS*96) + (size_t)row * 96 + col] = v;
        } else if (EPI == 6) {
          unsafeAtomicAdd(&outF[(size_t)row * DMODEL + col], v);
        }
      }
    }
  }
}

// ---------------------------------------------------------------------------
__global__ __launch_bounds__(256)
void reduce_xdbl_k(const float* __restrict__ part, float* __restrict__ xdbl,
                   __hip_bfloat16* __restrict__ dtH)
{
  int i = blockIdx.x * 256 + threadIdx.x;
  if (i >= ROWS*96) return;
  float s = 0.f;
#pragma unroll
  for (int kc = 0; kc < KSPLIT; ++kc) s += part[(size_t)kc*ROWS*96 + i];
  xdbl[i] = s;
  int row = i / 96, col = i - row*96;
  if (col < 64) dtH[(size_t)row*64 + col] = __float2bfloat16(s);
}

// ---------------------------------------------------------------------------
__global__ __launch_bounds__(256)
void conv_silu_k(const __hip_bfloat16* __restrict__ xi,
                 const float* __restrict__ cw,
                 const float* __restrict__ cb,
                 __hip_bfloat16* __restrict__ xcH)
{
  int idx = blockIdx.x * 256 + threadIdx.x;
  if (idx >= ROWS * DINNER) return;
  int d  = idx & (DINNER - 1);
  int t  = (idx >> 11) & (SEQ - 1);
  int bt = idx >> 11;
  float acc = cb[d];
#pragma unroll
  for (int i = 0; i < 4; ++i) {
    int tt = t - 3 + i;
    if (tt >= 0) acc += cw[d*4 + i] * bf2f(xi[(size_t)(bt - 3 + i) * DINNER + d]);
  }
  float y = acc * sigmoidf_(acc);
  xcH[idx] = __float2bfloat16(y);
}

// ---------------------------------------------------------------------------
// Chunked selective scan (lane layout validated R7): 4 lanes/channel,
// 4 states/lane, B/C staged per block in LDS, 2 shfl_xor reduce.
// GSTEP=8 (R10's GSTEP=16 REGRESSED: 6x16=96 prefetch floats pushed VGPR
// ~130 -> waves/SIMD stepped down at the 128 boundary (m69) -> lost TLP on
// a latency-bound kernel. ILP-vs-TLP tradeoff lands at 8 here.)
// ---------------------------------------------------------------------------
#define GSTEP 8

__global__ __launch_bounds__(256)
void stats_k(const float* __restrict__ delta,
             const __hip_bfloat16* __restrict__ xcH,
             const float* __restrict__ xdbl,
             const float* __restrict__ alF,
             float* __restrict__ Hc, float* __restrict__ Sd)
{
  __shared__ alignas(16) float Bs[CLEN*16];     // 4 KB
  const int bid  = blockIdx.x;                  // b*512 + c*32 + cg
  const int b    = bid >> 9;
  const int c    = (bid >> 5) & (NCHUNK-1);
  const int cg   = bid & 31;
  const int tid  = threadIdx.x;
  const int lane = tid & 63;
  const int wave = tid >> 6;
  const int sub  = lane & 3;
  const int ch   = (cg << 6) + (wave << 4) + (lane >> 2);

  const size_t rb = (size_t)b * SEQ + (size_t)c * CLEN;

  for (int i = tid; i < CLEN*16; i += 256) {
    int t = i >> 4, j = i & 15;
    Bs[i] = xdbl[(rb + t)*96 + 64 + j];
  }
  __syncthreads();

  float negA[4];
#pragma unroll
  for (int j = 0; j < 4; ++j) negA[j] = -__expf(alF[ch*NSTATE + sub*4 + j]);

  const float*          dp = delta + rb * DINNER + ch;
  const __hip_bfloat16* xp = xcH   + rb * DINNER + ch;

  float h0=0.f,h1=0.f,h2=0.f,h3=0.f, sd=0.f;
  float d0[GSTEP], x0[GSTEP], d1[GSTEP], x1[GSTEP];

#define PF1(D_,X_,T0) \
  _Pragma("unroll") \
  for (int u = 0; u < GSTEP; ++u) { \
    D_[u] = dp[(size_t)((T0)+u) * DINNER]; \
    X_[u] = bf2f(xp[(size_t)((T0)+u) * DINNER]); \
  }
#define ST1(D_,X_,T0) \
  _Pragma("unroll") \
  for (int u = 0; u < GSTEP; ++u) { \
    float d_ = D_[u]; \
    sd += d_; \
    float du = d_ * X_[u]; \
    f32x4 B4 = *(const f32x4*)&Bs[((T0)+u)*16 + sub*4]; \
    h0 = __expf(d_*negA[0])*h0 + du*B4.x; \
    h1 = __expf(d_*negA[1])*h1 + du*B4.y; \
    h2 = __expf(d_*negA[2])*h2 + du*B4.z; \
    h3 = __expf(d_*negA[3])*h3 + du*B4.w; \
  }

  PF1(d0, x0, 0)
  for (int t0 = 0; t0 < CLEN; t0 += 2*GSTEP) {
    PF1(d1, x1, t0 + GSTEP)
    ST1(d0, x0, t0)
    if (t0 + 2*GSTEP < CLEN) { PF1(d0, x0, t0 + 2*GSTEP) }
    ST1(d1, x1, t0 + GSTEP)
  }
#undef PF1
#undef ST1

  const size_t bc = (size_t)(b*NCHUNK + c);
  f32x4 hv = { h0, h1, h2, h3 };
  *(f32x4*)&Hc[(bc*DINNER + ch)*NSTATE + sub*4] = hv;
  if (sub == 0) Sd[bc*DINNER + ch] = sd;
}

__global__ __launch_bounds__(256)
void carry_k(const float* __restrict__ Hc, const float* __restrict__ Sd,
             const float* __restrict__ alF, float* __restrict__ hin)
{
  int i = blockIdx.x * 256 + threadIdx.x;       // BATCH*DINNER*NSTATE = 65536
  int n  = i & (NSTATE-1);
  int ch = (i >> 4) & (DINNER-1);
  int b  = i >> 15;
  float negA = -__expf(alF[ch * NSTATE + n]);
  float h = 0.f;
#pragma unroll
  for (int c = 0; c < NCHUNK; ++c) {
    size_t bc = (size_t)(b*NCHUNK + c);
    hin[(bc*DINNER + ch)*NSTATE + n] = h;
    float P = __expf(negA * Sd[bc*DINNER + ch]);
    h = P * h + Hc[(bc*DINNER + ch)*NSTATE + n];
  }
}

__global__ __launch_bounds__(256)
void emit_k(const float* __restrict__ delta,
            const __hip_bfloat16* __restrict__ xcH,
            const float* __restrict__ xdbl,
            const __hip_bfloat16* __restrict__ zsH,
            const float* __restrict__ alF,
            const float* __restrict__ DF,
            const float* __restrict__ hin,
            __hip_bfloat16* __restrict__ yH)
{
  __shared__ alignas(16) float BCs[CLEN*32];    // 8 KB
  const int bid  = blockIdx.x;
  const int b    = bid >> 9;
  const int c    = (bid >> 5) & (NCHUNK-1);
  const int cg   = bid & 31;
  const int tid  = threadIdx.x;
  const int lane = tid & 63;
  const int wave = tid >> 6;
  const int sub  = lane & 3;
  const int ch   = (cg << 6) + (wave << 4) + (lane >> 2);

  const size_t rb = (size_t)b * SEQ + (size_t)c * CLEN;

  for (int i = tid; i < CLEN*32; i += 256) {
    int t = i >> 5, j = i & 31;
    BCs[i] = xdbl[(rb + t)*96 + 64 + j];
  }
  __syncthreads();

  float negA[4];
#pragma unroll
  for (int j = 0; j < 4; ++j) negA[j] = -__expf(alF[ch*NSTATE + sub*4 + j]);
  const float Dch = DF[ch];

  const float*          dp = delta + rb * DINNER + ch;
  const __hip_bfloat16* xp = xcH   + rb * DINNER + ch;
  const __hip_bfloat16* zp = zsH   + rb * DINNER + ch;
  __hip_bfloat16*       yp = yH    + rb * DINNER + ch;

  f32x4 hv = *(const f32x4*)&hin[((size_t)(b*NCHUNK + c)*DINNER + ch)*NSTATE + sub*4];
  float h0=hv.x, h1=hv.y, h2=hv.z, h3=hv.w;

  float d0[GSTEP], x0[GSTEP], z0[GSTEP], d1[GSTEP], x1[GSTEP], z1[GSTEP];

#define PF(D_,X_,Z_,T0) \
  _Pragma("unroll") \
  for (int u = 0; u < GSTEP; ++u) { \
    D_[u] = dp[(size_t)((T0)+u) * DINNER]; \
    X_[u] = bf2f(xp[(size_t)((T0)+u) * DINNER]); \
    Z_[u] = bf2f(zp[(size_t)((T0)+u) * DINNER]); \
  }
#define STEPS(D_,X_,Z_,T0) \
  _Pragma("unroll") \
  for (int u = 0; u < GSTEP; ++u) { \
    float d_ = D_[u]; \
    float du = d_ * X_[u]; \
    f32x4 B4 = *(const f32x4*)&BCs[((T0)+u)*32 + sub*4]; \
    f32x4 C4 = *(const f32x4*)&BCs[((T0)+u)*32 + 16 + sub*4]; \
    h0 = __expf(d_*negA[0])*h0 + du*B4.x; \
    h1 = __expf(d_*negA[1])*h1 + du*B4.y; \
    h2 = __expf(d_*negA[2])*h2 + du*B4.z; \
    h3 = __expf(d_*negA[3])*h3 + du*B4.w; \
    float p = h0*C4.x + h1*C4.y + h2*C4.z + h3*C4.w; \
    p += __shfl_xor(p, 1); \
    p += __shfl_xor(p, 2); \
    if (sub == 0) { \
      float y = (p + X_[u] * Dch) * Z_[u]; \
      yp[(size_t)((T0)+u) * DINNER] = __float2bfloat16(y); \
    } \
  }

  PF(d0, x0, z0, 0)
  for (int t0 = 0; t0 < CLEN; t0 += 2*GSTEP) {
    PF(d1, x1, z1, t0 + GSTEP)
    STEPS(d0, x0, z0, t0)
    if (t0 + 2*GSTEP < CLEN) { PF(d0, x0, z0, t0 + 2*GSTEP) }
    STEPS(d1, x1, z1, t0 + GSTEP)
  }
#undef PF
#undef STEPS
}

// ---------------------------------------------------------------------------
extern "C" void kernel_launch(void* const* d_in, const int* in_sizes, int n_in,
                              void* d_out, int out_size, void* d_ws, size_t ws_size,
                              hipStream_t stream)
{
  float* out = (float*)d_out;   // reference output dtype: float32
  char* ws = (char*)d_ws;
  const size_t MB = 1024*1024;

  // workspace layout (68 MB, liveness-aliased)
  int*            flag    = (int*)            (ws);
  float*          cwF     = (float*)          (ws + 1024);
  float*          cbF     = (float*)          (ws + 40*1024);
  float*          dtbF    = (float*)          (ws + 56*1024);
  float*          alF     = (float*)          (ws + 72*1024);
  float*          DF      = (float*)          (ws + 208*1024);
  float*          Sd      = (float*)          (ws + 256*1024);      // 256 KB
  __hip_bfloat16* xB      = (__hip_bfloat16*) (ws + 1*MB);          // 4 MB  (dead after G1)
  __hip_bfloat16* inpB    = (__hip_bfloat16*) (ws + 5*MB);          // 8 MB  (dead after G1)
  __hip_bfloat16* xiB     = (__hip_bfloat16*) (ws + 13*MB);         // 8 MB  (dead after conv)
  float*          part    = (float*)          (ws + 1*MB);          // 12 MB aliases xB/inpB
  float*          dlt     = (float*)          (ws + 1*MB);          // 16 MB aliases part/xiB[:4MB]
  __hip_bfloat16* xprojB  = (__hip_bfloat16*) (ws + 21*MB);
  __hip_bfloat16* dtprojB = (__hip_bfloat16*) (ws + 21*MB + 512*1024);
  __hip_bfloat16* outpB   = (__hip_bfloat16*) (ws + 22*MB);         // 4 MB
  __hip_bfloat16* zsH     = (__hip_bfloat16*) (ws + 26*MB);         // 8 MB (bf16 silu(z))
  __hip_bfloat16* xcH     = (__hip_bfloat16*) (ws + 42*MB);         // 8 MB
  float*          xdbl    = (float*)          (ws + 50*MB);         // 768 KB
  __hip_bfloat16* dtH     = (__hip_bfloat16*) (ws + 51*MB);         // 256 KB
  __hip_bfloat16* yH      = (__hip_bfloat16*) (ws + 52*MB);         // 8 MB
  float*          Hc      = (float*)          (ws + 60*MB);         // 4 MB
  float*          hin     = (float*)          (ws + 64*MB);         // 4 MB -> top 68 MB

  dim3 blk(256);

  // 0) sniff (1 tiny block) + vectorized canonicalize (+ d_out zero-init)
  sniff_k<<<1, 64, 0, stream>>>((const unsigned short*)d_in[0], flag);
  CvtArgs ca = { d_in[0], d_in[1], d_in[2], d_in[3], d_in[4],
                 d_in[5], d_in[6], d_in[7], d_in[8], d_in[9],
                 xB, inpB, xprojB, dtprojB, outpB,
                 cwF, cbF, dtbF, alF, DF, out, flag };
  convert_all_k<<<CVT_BLOCKS, blk, 0, stream>>>(ca);

  // 1) in_proj (2048 x 4096 x 1024): split -> xi bf16, silu(z) bf16
  gemm64<4><<<dim3(4096/128, ROWS/128), blk, 0, stream>>>(
      xB, inpB, ROWS, 2*DINNER, DMODEL, 0, nullptr, xiB, zsH, nullptr);

  // 2) xc = silu(depthwise_conv(xi) + b)
  conv_silu_k<<<(ROWS*DINNER)/256, blk, 0, stream>>>(xiB, cwF, cbF, xcH);

  // 3) x_dbl (2048 x 96 x 2048): 16-way split-K + reduce
  gemm64<5><<<dim3(1, ROWS/128, KSPLIT), blk, 0, stream>>>(
      xcH, xprojB, ROWS, 96, DINNER, DINNER/KSPLIT, part, nullptr, nullptr, nullptr);
  reduce_xdbl_k<<<(ROWS*96+255)/256, blk, 0, stream>>>(part, xdbl, dtH);

  // 4) delta = softplus(dt @ dt_proj^T + dt_b) (2048 x 2048 x 64): single K-iter
  gemm64<3><<<dim3(DINNER/128, ROWS/128), blk, 0, stream>>>(
      dtH, dtprojB, ROWS, DINNER, DTRANK, 0, dlt, nullptr, nullptr, dtbF);

  // 5) chunked selective scan + fused combine -> bf16 yH
  stats_k<<<BATCH*NCHUNK*32, blk, 0, stream>>>(dlt, xcH, xdbl, alF, Hc, Sd);
  carry_k<<<(BATCH*DINNER*NSTATE)/256, blk, 0, stream>>>(Hc, Sd, alF, hin);
  emit_k<<<BATCH*NCHUNK*32, blk, 0, stream>>>(dlt, xcH, xdbl, zsH, alF, DF, hin, yH);

  // 6) out_proj (2048 x 1024 x 2048): split-K=4, atomic accumulate into d_out
  gemm64<6><<<dim3(DMODEL/128, ROWS/128, 4), blk, 0, stream>>>(
      yH, outpB, ROWS, DMODEL, DINNER, DINNER/4, out, nullptr, nullptr, nullptr);
}

// Round 12
// 249.324 us; speedup vs baseline: 1.1057x; 1.0054x over previous
//
#include <hip/hip_runtime.h>
#include <hip/hip_bf16.h>
#include <cstdint>
#include <cstddef>

#define DMODEL 1024
#define DINNER 2048
#define NSTATE 16
#define DTRANK 64
#define BATCH 2
#define SEQ 1024
#define ROWS (BATCH*SEQ)   // 2048 token rows
#define NCHUNK 16
#define CLEN (SEQ/NCHUNK)  // 64
#define KSPLIT 16          // split-K ways for x_proj GEMM

typedef __attribute__((ext_vector_type(8))) short short8;
typedef __attribute__((ext_vector_type(4))) short short4v;
typedef __attribute__((ext_vector_type(4))) float f32x4;

__device__ __forceinline__ float bf2f(__hip_bfloat16 h){ return __bfloat162float(h); }
__device__ __forceinline__ float sigmoidf_(float x){ return 1.0f/(1.0f + __expf(-x)); }
__device__ __forceinline__ unsigned short f2bfbits(float v){
  __hip_bfloat16 h = __float2bfloat16(v);
  return *(unsigned short*)&h;
}
__device__ __forceinline__ float bfbits2f(unsigned short u){
  unsigned int x = ((unsigned int)u) << 16;
  return *(float*)&x;
}

__device__ __forceinline__ void gld16(const void* g, void* l){
  __builtin_amdgcn_global_load_lds((const __attribute__((address_space(1))) void*)g,
                                   (__attribute__((address_space(3))) void*)l, 16, 0, 0);
}

// ---------------------------------------------------------------------------
// dtype sniffer — separate tiny kernel (R8 lesson: inlining per-thread in the
// convert kernel cost +30us of VMEM issue).
// ---------------------------------------------------------------------------
__global__ void sniff_k(const unsigned short* __restrict__ xu, int* __restrict__ flag)
{
  int t = threadIdx.x;           // 64 threads
  int cnt = 0;
  for (int i = t; i < 1024; i += 64) {
    unsigned short u = xu[i];
    int e = (u >> 7) & 0xFF;
    if (e >= 0x70 && e <= 0x86) cnt++;
  }
  for (int o = 32; o; o >>= 1) cnt += __shfl_down(cnt, o);
  if (t == 0) *flag = (cnt >= 768) ? 0 : 1;
}

// ---------------------------------------------------------------------------
// Fused canonicalizer, x4 vectorized (validated R10/R11) + zero-init of
// d_out (2M f32, blocks 0..2047) and xdbl (196608 f32, blocks 2048..2239 —
// the x_proj split-K now atomically accumulates into xdbl).
// ---------------------------------------------------------------------------
struct CvtArgs {
  const void *s0,*s1,*s2,*s3,*s4,*s5,*s6,*s7,*s8,*s9;
  __hip_bfloat16 *xB,*inpB,*xprojB,*dtprojB,*outpB;
  float *cwF,*cbF,*dtbF,*alF,*DF;
  float *outZ, *xdblZ;
  const int* flag;
};
#define CVT_C1 2097152
#define CVT_C2 6291456
#define CVT_C3 6299648
#define CVT_C4 6301696
#define CVT_C5 6498304
#define CVT_C6 6629376
#define CVT_C7 6631424
#define CVT_C8 6664192
#define CVT_C9 6666240
#define CVT_TOT 8763392
#define CVT_BLOCKS (CVT_TOT/4/256)   // 8558

__device__ __forceinline__ void cvt_read4(const void* s, int j, int fl, float v[4]){
  if (fl) {
    f32x4 t = ((const f32x4*)s)[j>>2];
    v[0]=t.x; v[1]=t.y; v[2]=t.z; v[3]=t.w;
  } else {
    short4v t = *(const short4v*)((const __hip_bfloat16*)s + j);
    v[0]=bfbits2f((unsigned short)t.x); v[1]=bfbits2f((unsigned short)t.y);
    v[2]=bfbits2f((unsigned short)t.z); v[3]=bfbits2f((unsigned short)t.w);
  }
}
__device__ __forceinline__ void cvt_wB(__hip_bfloat16* d, int j, const float v[4]){
  short4v o;
  o.x=(short)f2bfbits(v[0]); o.y=(short)f2bfbits(v[1]);
  o.z=(short)f2bfbits(v[2]); o.w=(short)f2bfbits(v[3]);
  *(short4v*)(d + j) = o;
}
__device__ __forceinline__ void cvt_wF(float* d, int j, const float v[4]){
  f32x4 o = { v[0], v[1], v[2], v[3] };
  *(f32x4*)(d + j) = o;
}

__global__ __launch_bounds__(256)
void convert_all_k(CvtArgs a)
{
  int i4 = blockIdx.x * 256 + threadIdx.x;
  const int fl = *a.flag;

  f32x4 z = {0.f, 0.f, 0.f, 0.f};
  if (blockIdx.x < 2048) {
    ((f32x4*)a.outZ)[i4] = z;                       // d_out: 2M f32
  } else if (blockIdx.x < 2048 + 192) {
    ((f32x4*)a.xdblZ)[i4 - 2048*256] = z;           // xdbl: 196608 f32 exactly
  }

  int i = i4 * 4;
  if (i >= CVT_TOT) return;
  float v[4];
  if (i < CVT_C1)      { cvt_read4(a.s0, i, fl, v);        cvt_wB(a.xB, i, v); }
  else if (i < CVT_C2) { cvt_read4(a.s1, i-CVT_C1, fl, v); cvt_wB(a.inpB, i-CVT_C1, v); }
  else if (i < CVT_C3) { cvt_read4(a.s2, i-CVT_C2, fl, v); cvt_wF(a.cwF, i-CVT_C2, v); }
  else if (i < CVT_C4) { cvt_read4(a.s3, i-CVT_C3, fl, v); cvt_wF(a.cbF, i-CVT_C3, v); }
  else if (i < CVT_C5) { cvt_read4(a.s4, i-CVT_C4, fl, v); cvt_wB(a.xprojB, i-CVT_C4, v); }
  else if (i < CVT_C6) { cvt_read4(a.s5, i-CVT_C5, fl, v); cvt_wB(a.dtprojB, i-CVT_C5, v); }
  else if (i < CVT_C7) { cvt_read4(a.s6, i-CVT_C6, fl, v); cvt_wF(a.dtbF, i-CVT_C6, v); }
  else if (i < CVT_C8) { cvt_read4(a.s7, i-CVT_C7, fl, v); cvt_wF(a.alF, i-CVT_C7, v); }
  else if (i < CVT_C9) { cvt_read4(a.s8, i-CVT_C8, fl, v); cvt_wF(a.DF, i-CVT_C8, v); }
  else                 { cvt_read4(a.s9, i-CVT_C9, fl, v); cvt_wB(a.outpB, i-CVT_C9, v); }
}

// ---------------------------------------------------------------------------
// NT GEMM (validated R8/R9): BK=64, XOR-swizzled LDS staging.
// EPI: 3 = softplus(acc + biasF[col]) -> f32 (delta)
//      4 = in_proj split: col<2048 -> bf16 xi (outH); col>=2048 -> silu -> bf16 outH2
//      5 = split-K atomic into f32 xdbl [row,96] (x_proj; R11's part-buffer
//          round-trip = 24 MB + a reduce launch, removed)
//      6 = split-K atomic: unsafeAtomicAdd into outF [row,DMODEL] (out_proj)
// ---------------------------------------------------------------------------
template<int EPI>
__global__ __launch_bounds__(256)
void gemm64(const __hip_bfloat16* __restrict__ A,
            const __hip_bfloat16* __restrict__ W,
            int M, int N, int K, int kchunk,
            float* __restrict__ outF,
            __hip_bfloat16* __restrict__ outH,
            __hip_bfloat16* __restrict__ outH2,
            const float* __restrict__ biasF)
{
  __shared__ alignas(16) __hip_bfloat16 As[128*64];   // 16 KB
  __shared__ alignas(16) __hip_bfloat16 Ws[128*64];   // 16 KB
  const int tid  = threadIdx.x;
  const int lane = tid & 63;
  const int wave = tid >> 6;
  const int wm = wave & 1, wn = wave >> 1;
  const int row0 = blockIdx.y * 128;
  const int col0 = blockIdx.x * 128;

  f32x4 acc[4][4] = {};

  int kbeg = 0, kend = K;
  if (EPI == 5 || EPI == 6) { kbeg = blockIdx.z * kchunk; kend = kbeg + kchunk; }

  const int r16 = lane & 15, q = lane >> 4;
  const int sx0 = ((q ^ (r16 & 7)) * 16);

  for (int k0 = kbeg; k0 < kend; k0 += 64) {
#pragma unroll
    for (int j = 0; j < 4; ++j) {             // A tile
      int e = tid + j*256;
      int r = e >> 3, g = e & 7;
      int kc = ((g ^ (r & 7)) << 3);
      gld16(A + (size_t)(row0 + r) * K + k0 + kc, (char*)As + (size_t)e*16);
    }
#pragma unroll
    for (int j = 0; j < 4; ++j) {             // W tile
      int e = tid + j*256;
      int r = e >> 3, g = e & 7;
      int kc = ((g ^ (r & 7)) << 3);
      int rw = col0 + r; if (EPI == 5 && rw > N-1) rw = N-1;
      gld16(W + (size_t)rw * K + k0 + kc, (char*)Ws + (size_t)e*16);
    }
    __syncthreads();

    const char* Ab = (const char*)As + ((wm*64 + r16) * 128);
    const char* Wb = (const char*)Ws + ((wn*64 + r16) * 128);
#pragma unroll
    for (int ksub = 0; ksub < 2; ++ksub) {
      const int sx = sx0 ^ (ksub * 64);
      short8 af[4], wf[4];
#pragma unroll
      for (int i = 0; i < 4; ++i) af[i] = *(const short8*)(Ab + i*16*128 + sx);
#pragma unroll
      for (int i = 0; i < 4; ++i) wf[i] = *(const short8*)(Wb + i*16*128 + sx);
#pragma unroll
      for (int mt = 0; mt < 4; ++mt)
#pragma unroll
        for (int nt = 0; nt < 4; ++nt)
          acc[mt][nt] = __builtin_amdgcn_mfma_f32_16x16x32_bf16(af[mt], wf[nt], acc[mt][nt], 0, 0, 0);
    }
    __syncthreads();
  }

  // C/D layout (verified m89/m91): col = lane&15, row = (lane>>4)*4 + r
  const int mbase = row0 + wm*64 + (q * 4);
  const int nbase = col0 + wn*64 + r16;

  float bv[4];
  if (EPI == 3) {
#pragma unroll
    for (int nt = 0; nt < 4; ++nt) bv[nt] = biasF[nbase + nt*16];
  }

#pragma unroll
  for (int mt = 0; mt < 4; ++mt) {
#pragma unroll
    for (int nt = 0; nt < 4; ++nt) {
#pragma unroll
      for (int r = 0; r < 4; ++r) {
        int row = mbase + mt*16 + r;
        int col = nbase + nt*16;
        float v = acc[mt][nt][r];
        if (EPI == 3) {
          v += bv[nt];
          float sp = fmaxf(v, 0.0f) + __logf(1.0f + __expf(-fabsf(v)));
          outF[(size_t)row * DINNER + col] = sp;
        } else if (EPI == 4) {
          if (col < DINNER) {
            outH[(size_t)row * DINNER + col] = __float2bfloat16(v);
          } else {
            outH2[(size_t)row * DINNER + (col - DINNER)] = __float2bfloat16(v * sigmoidf_(v));
          }
        } else if (EPI == 5) {
          if (col < 96)
            unsafeAtomicAdd(&outF[(size_t)row * 96 + col], v);
        } else if (EPI == 6) {
          unsafeAtomicAdd(&outF[(size_t)row * DMODEL + col], v);
        }
      }
    }
  }
}

// ---------------------------------------------------------------------------
// dt bf16 copy from completed xdbl (replaces R11's 24MB part-reduce pass)
// ---------------------------------------------------------------------------
__global__ __launch_bounds__(256)
void dt_cvt_k(const float* __restrict__ xdbl, __hip_bfloat16* __restrict__ dtH)
{
  int i = blockIdx.x * 256 + threadIdx.x;     // ROWS*64 = 131072
  if (i >= ROWS*64) return;
  int row = i >> 6, col = i & 63;
  dtH[i] = __float2bfloat16(xdbl[(size_t)row*96 + col]);
}

// ---------------------------------------------------------------------------
// Depthwise causal conv + bias + SiLU, x4 vectorized over channels
// (scalar version issued 5 VMEM insts/element across 4.2M threads).
// t is uniform across the 4 channels -> boundary branch stays wave-uniform.
// ---------------------------------------------------------------------------
__global__ __launch_bounds__(256)
void conv_silu_k(const __hip_bfloat16* __restrict__ xi,
                 const float* __restrict__ cw,
                 const float* __restrict__ cb,
                 __hip_bfloat16* __restrict__ xcH)
{
  int idx4 = blockIdx.x * 256 + threadIdx.x;   // ROWS*DINNER/4 threads
  int idx  = idx4 * 4;
  int d  = idx & (DINNER - 1);
  int t  = (idx >> 11) & (SEQ - 1);
  int bt = idx >> 11;

  f32x4 cb4 = *(const f32x4*)&cb[d];
  float a0=cb4.x, a1=cb4.y, a2=cb4.z, a3=cb4.w;
  f32x4 w0 = *(const f32x4*)&cw[(d+0)*4];   // [tap0..3] for channel d+0
  f32x4 w1 = *(const f32x4*)&cw[(d+1)*4];
  f32x4 w2 = *(const f32x4*)&cw[(d+2)*4];
  f32x4 w3 = *(const f32x4*)&cw[(d+3)*4];

#pragma unroll
  for (int i = 0; i < 4; ++i) {
    if (t - 3 + i >= 0) {
      short4v xv = *(const short4v*)(xi + (size_t)(bt - 3 + i) * DINNER + d);
      float x0 = bfbits2f((unsigned short)xv.x);
      float x1 = bfbits2f((unsigned short)xv.y);
      float x2 = bfbits2f((unsigned short)xv.z);
      float x3 = bfbits2f((unsigned short)xv.w);
      float c0 = (i==0)?w0.x:(i==1)?w0.y:(i==2)?w0.z:w0.w;
      float c1 = (i==0)?w1.x:(i==1)?w1.y:(i==2)?w1.z:w1.w;
      float c2 = (i==0)?w2.x:(i==1)?w2.y:(i==2)?w2.z:w2.w;
      float c3 = (i==0)?w3.x:(i==1)?w3.y:(i==2)?w3.z:w3.w;
      a0 += c0*x0; a1 += c1*x1; a2 += c2*x2; a3 += c3*x3;
    }
  }
  float y0 = a0 * sigmoidf_(a0);
  float y1 = a1 * sigmoidf_(a1);
  float y2 = a2 * sigmoidf_(a2);
  float y3 = a3 * sigmoidf_(a3);
  short4v o;
  o.x=(short)f2bfbits(y0); o.y=(short)f2bfbits(y1);
  o.z=(short)f2bfbits(y2); o.w=(short)f2bfbits(y3);
  *(short4v*)(xcH + idx) = o;
}

// ---------------------------------------------------------------------------
// Chunked selective scan (lane layout validated R7, GSTEP=8 validated R11 —
// GSTEP=16 regressed via the VGPR-128 occupancy step, m69).
// ---------------------------------------------------------------------------
#define GSTEP 8

__global__ __launch_bounds__(256)
void stats_k(const float* __restrict__ delta,
             const __hip_bfloat16* __restrict__ xcH,
             const float* __restrict__ xdbl,
             const float* __restrict__ alF,
             float* __restrict__ Hc, float* __restrict__ Sd)
{
  __shared__ alignas(16) float Bs[CLEN*16];     // 4 KB
  const int bid  = blockIdx.x;                  // b*512 + c*32 + cg
  const int b    = bid >> 9;
  const int c    = (bid >> 5) & (NCHUNK-1);
  const int cg   = bid & 31;
  const int tid  = threadIdx.x;
  const int lane = tid & 63;
  const int wave = tid >> 6;
  const int sub  = lane & 3;
  const int ch   = (cg << 6) + (wave << 4) + (lane >> 2);

  const size_t rb = (size_t)b * SEQ + (size_t)c * CLEN;

  for (int i = tid; i < CLEN*16; i += 256) {
    int t = i >> 4, j = i & 15;
    Bs[i] = xdbl[(rb + t)*96 + 64 + j];
  }
  __syncthreads();

  float negA[4];
#pragma unroll
  for (int j = 0; j < 4; ++j) negA[j] = -__expf(alF[ch*NSTATE + sub*4 + j]);

  const float*          dp = delta + rb * DINNER + ch;
  const __hip_bfloat16* xp = xcH   + rb * DINNER + ch;

  float h0=0.f,h1=0.f,h2=0.f,h3=0.f, sd=0.f;
  float d0[GSTEP], x0[GSTEP], d1[GSTEP], x1[GSTEP];

#define PF1(D_,X_,T0) \
  _Pragma("unroll") \
  for (int u = 0; u < GSTEP; ++u) { \
    D_[u] = dp[(size_t)((T0)+u) * DINNER]; \
    X_[u] = bf2f(xp[(size_t)((T0)+u) * DINNER]); \
  }
#define ST1(D_,X_,T0) \
  _Pragma("unroll") \
  for (int u = 0; u < GSTEP; ++u) { \
    float d_ = D_[u]; \
    sd += d_; \
    float du = d_ * X_[u]; \
    f32x4 B4 = *(const f32x4*)&Bs[((T0)+u)*16 + sub*4]; \
    h0 = __expf(d_*negA[0])*h0 + du*B4.x; \
    h1 = __expf(d_*negA[1])*h1 + du*B4.y; \
    h2 = __expf(d_*negA[2])*h2 + du*B4.z; \
    h3 = __expf(d_*negA[3])*h3 + du*B4.w; \
  }

  PF1(d0, x0, 0)
  for (int t0 = 0; t0 < CLEN; t0 += 2*GSTEP) {
    PF1(d1, x1, t0 + GSTEP)
    ST1(d0, x0, t0)
    if (t0 + 2*GSTEP < CLEN) { PF1(d0, x0, t0 + 2*GSTEP) }
    ST1(d1, x1, t0 + GSTEP)
  }
#undef PF1
#undef ST1

  const size_t bc = (size_t)(b*NCHUNK + c);
  f32x4 hv = { h0, h1, h2, h3 };
  *(f32x4*)&Hc[(bc*DINNER + ch)*NSTATE + sub*4] = hv;
  if (sub == 0) Sd[bc*DINNER + ch] = sd;
}

__global__ __launch_bounds__(256)
void carry_k(const float* __restrict__ Hc, const float* __restrict__ Sd,
             const float* __restrict__ alF, float* __restrict__ hin)
{
  int i = blockIdx.x * 256 + threadIdx.x;       // BATCH*DINNER*NSTATE = 65536
  int n  = i & (NSTATE-1);
  int ch = (i >> 4) & (DINNER-1);
  int b  = i >> 15;
  float negA = -__expf(alF[ch * NSTATE + n]);
  float h = 0.f;
#pragma unroll
  for (int c = 0; c < NCHUNK; ++c) {
    size_t bc = (size_t)(b*NCHUNK + c);
    hin[(bc*DINNER + ch)*NSTATE + n] = h;
    float P = __expf(negA * Sd[bc*DINNER + ch]);
    h = P * h + Hc[(bc*DINNER + ch)*NSTATE + n];
  }
}

__global__ __launch_bounds__(256)
void emit_k(const float* __restrict__ delta,
            const __hip_bfloat16* __restrict__ xcH,
            const float* __restrict__ xdbl,
            const __hip_bfloat16* __restrict__ zsH,
            const float* __restrict__ alF,
            const float* __restrict__ DF,
            const float* __restrict__ hin,
            __hip_bfloat16* __restrict__ yH)
{
  __shared__ alignas(16) float BCs[CLEN*32];    // 8 KB
  const int bid  = blockIdx.x;
  const int b    = bid >> 9;
  const int c    = (bid >> 5) & (NCHUNK-1);
  const int cg   = bid & 31;
  const int tid  = threadIdx.x;
  const int lane = tid & 63;
  const int wave = tid >> 6;
  const int sub  = lane & 3;
  const int ch   = (cg << 6) + (wave << 4) + (lane >> 2);

  const size_t rb = (size_t)b * SEQ + (size_t)c * CLEN;

  for (int i = tid; i < CLEN*32; i += 256) {
    int t = i >> 5, j = i & 31;
    BCs[i] = xdbl[(rb + t)*96 + 64 + j];
  }
  __syncthreads();

  float negA[4];
#pragma unroll
  for (int j = 0; j < 4; ++j) negA[j] = -__expf(alF[ch*NSTATE + sub*4 + j]);
  const float Dch = DF[ch];

  const float*          dp = delta + rb * DINNER + ch;
  const __hip_bfloat16* xp = xcH   + rb * DINNER + ch;
  const __hip_bfloat16* zp = zsH   + rb * DINNER + ch;
  __hip_bfloat16*       yp = yH    + rb * DINNER + ch;

  f32x4 hv = *(const f32x4*)&hin[((size_t)(b*NCHUNK + c)*DINNER + ch)*NSTATE + sub*4];
  float h0=hv.x, h1=hv.y, h2=hv.z, h3=hv.w;

  float d0[GSTEP], x0[GSTEP], z0[GSTEP], d1[GSTEP], x1[GSTEP], z1[GSTEP];

#define PF(D_,X_,Z_,T0) \
  _Pragma("unroll") \
  for (int u = 0; u < GSTEP; ++u) { \
    D_[u] = dp[(size_t)((T0)+u) * DINNER]; \
    X_[u] = bf2f(xp[(size_t)((T0)+u) * DINNER]); \
    Z_[u] = bf2f(zp[(size_t)((T0)+u) * DINNER]); \
  }
#define STEPS(D_,X_,Z_,T0) \
  _Pragma("unroll") \
  for (int u = 0; u < GSTEP; ++u) { \
    float d_ = D_[u]; \
    float du = d_ * X_[u]; \
    f32x4 B4 = *(const f32x4*)&BCs[((T0)+u)*32 + sub*4]; \
    f32x4 C4 = *(const f32x4*)&BCs[((T0)+u)*32 + 16 + sub*4]; \
    h0 = __expf(d_*negA[0])*h0 + du*B4.x; \
    h1 = __expf(d_*negA[1])*h1 + du*B4.y; \
    h2 = __expf(d_*negA[2])*h2 + du*B4.z; \
    h3 = __expf(d_*negA[3])*h3 + du*B4.w; \
    float p = h0*C4.x + h1*C4.y + h2*C4.z + h3*C4.w; \
    p += __shfl_xor(p, 1); \
    p += __shfl_xor(p, 2); \
    if (sub == 0) { \
      float y = (p + X_[u] * Dch) * Z_[u]; \
      yp[(size_t)((T0)+u) * DINNER] = __float2bfloat16(y); \
    } \
  }

  PF(d0, x0, z0, 0)
  for (int t0 = 0; t0 < CLEN; t0 += 2*GSTEP) {
    PF(d1, x1, z1, t0 + GSTEP)
    STEPS(d0, x0, z0, t0)
    if (t0 + 2*GSTEP < CLEN) { PF(d0, x0, z0, t0 + 2*GSTEP) }
    STEPS(d1, x1, z1, t0 + GSTEP)
  }
#undef PF
#undef STEPS
}

// ---------------------------------------------------------------------------
extern "C" void kernel_launch(void* const* d_in, const int* in_sizes, int n_in,
                              void* d_out, int out_size, void* d_ws, size_t ws_size,
                              hipStream_t stream)
{
  float* out = (float*)d_out;   // reference output dtype: float32
  char* ws = (char*)d_ws;
  const size_t MB = 1024*1024;

  // workspace layout (68 MB, liveness-aliased)
  int*            flag    = (int*)            (ws);
  float*          cwF     = (float*)          (ws + 1024);
  float*          cbF     = (float*)          (ws + 40*1024);
  float*          dtbF    = (float*)          (ws + 56*1024);
  float*          alF     = (float*)          (ws + 72*1024);
  float*          DF      = (float*)          (ws + 208*1024);
  float*          Sd      = (float*)          (ws + 256*1024);      // 256 KB
  __hip_bfloat16* xB      = (__hip_bfloat16*) (ws + 1*MB);          // 4 MB  (dead after G1)
  __hip_bfloat16* inpB    = (__hip_bfloat16*) (ws + 5*MB);          // 8 MB  (dead after G1)
  __hip_bfloat16* xiB     = (__hip_bfloat16*) (ws + 13*MB);         // 8 MB  (dead after conv)
  float*          dlt     = (float*)          (ws + 1*MB);          // 16 MB aliases xB/inpB/xiB[:4MB]
  __hip_bfloat16* xprojB  = (__hip_bfloat16*) (ws + 21*MB);
  __hip_bfloat16* dtprojB = (__hip_bfloat16*) (ws + 21*MB + 512*1024);
  __hip_bfloat16* outpB   = (__hip_bfloat16*) (ws + 22*MB);         // 4 MB
  __hip_bfloat16* zsH     = (__hip_bfloat16*) (ws + 26*MB);         // 8 MB (bf16 silu(z))
  __hip_bfloat16* xcH     = (__hip_bfloat16*) (ws + 42*MB);         // 8 MB
  float*          xdbl    = (float*)          (ws + 50*MB);         // 768 KB
  __hip_bfloat16* dtH     = (__hip_bfloat16*) (ws + 51*MB);         // 256 KB
  __hip_bfloat16* yH      = (__hip_bfloat16*) (ws + 52*MB);         // 8 MB
  float*          Hc      = (float*)          (ws + 60*MB);         // 4 MB
  float*          hin     = (float*)          (ws + 64*MB);         // 4 MB -> top 68 MB

  dim3 blk(256);

  // 0) sniff (1 tiny block) + vectorized canonicalize (+ d_out/xdbl zero-init)
  sniff_k<<<1, 64, 0, stream>>>((const unsigned short*)d_in[0], flag);
  CvtArgs ca = { d_in[0], d_in[1], d_in[2], d_in[3], d_in[4],
                 d_in[5], d_in[6], d_in[7], d_in[8], d_in[9],
                 xB, inpB, xprojB, dtprojB, outpB,
                 cwF, cbF, dtbF, alF, DF, out, xdbl, flag };
  convert_all_k<<<CVT_BLOCKS, blk, 0, stream>>>(ca);

  // 1) in_proj (2048 x 4096 x 1024): split -> xi bf16, silu(z) bf16
  gemm64<4><<<dim3(4096/128, ROWS/128), blk, 0, stream>>>(
      xB, inpB, ROWS, 2*DINNER, DMODEL, 0, nullptr, xiB, zsH, nullptr);

  // 2) xc = silu(depthwise_conv(xi) + b), x4 vectorized
  conv_silu_k<<<(ROWS*DINNER/4)/256, blk, 0, stream>>>(xiB, cwF, cbF, xcH);

  // 3) x_dbl (2048 x 96 x 2048): 16-way split-K, atomic into zeroed xdbl
  gemm64<5><<<dim3(1, ROWS/128, KSPLIT), blk, 0, stream>>>(
      xcH, xprojB, ROWS, 96, DINNER, DINNER/KSPLIT, xdbl, nullptr, nullptr, nullptr);
  dt_cvt_k<<<(ROWS*64)/256, blk, 0, stream>>>(xdbl, dtH);

  // 4) delta = softplus(dt @ dt_proj^T + dt_b) (2048 x 2048 x 64): single K-iter
  gemm64<3><<<dim3(DINNER/128, ROWS/128), blk, 0, stream>>>(
      dtH, dtprojB, ROWS, DINNER, DTRANK, 0, dlt, nullptr, nullptr, dtbF);

  // 5) chunked selective scan + fused combine -> bf16 yH
  stats_k<<<BATCH*NCHUNK*32, blk, 0, stream>>>(dlt, xcH, xdbl, alF, Hc, Sd);
  carry_k<<<(BATCH*DINNER*NSTATE)/256, blk, 0, stream>>>(Hc, Sd, alF, hin);
  emit_k<<<BATCH*NCHUNK*32, blk, 0, stream>>>(dlt, xcH, xdbl, zsH, alF, DF, hin, yH);

  // 6) out_proj (2048 x 1024 x 2048): split-K=4, atomic accumulate into d_out
  gemm64<6><<<dim3(DMODEL/128, ROWS/128, 4), blk, 0, stream>>>(
      yH, outpB, ROWS, DMODEL, DINNER, DINNER/4, out, nullptr, nullptr, nullptr);
}

// Round 13
// 231.775 us; speedup vs baseline: 1.1895x; 1.0757x over previous
//
#include <hip/hip_runtime.h>
#include <hip/hip_bf16.h>
#include <cstdint>
#include <cstddef>

#define DMODEL 1024
#define DINNER 2048
#define NSTATE 16
#define DTRANK 64
#define BATCH 2
#define SEQ 1024
#define ROWS (BATCH*SEQ)   // 2048 token rows
#define NCHUNK 32
#define CLEN (SEQ/NCHUNK)  // 32
#define KSPLIT 16          // split-K ways for x_proj GEMM

typedef __attribute__((ext_vector_type(8))) short short8;
typedef __attribute__((ext_vector_type(4))) short short4v;
typedef __attribute__((ext_vector_type(4))) float f32x4;

__device__ __forceinline__ float bf2f(__hip_bfloat16 h){ return __bfloat162float(h); }
__device__ __forceinline__ float sigmoidf_(float x){ return 1.0f/(1.0f + __expf(-x)); }
__device__ __forceinline__ unsigned short f2bfbits(float v){
  __hip_bfloat16 h = __float2bfloat16(v);
  return *(unsigned short*)&h;
}
__device__ __forceinline__ float bfbits2f(unsigned short u){
  unsigned int x = ((unsigned int)u) << 16;
  return *(float*)&x;
}

__device__ __forceinline__ void gld16(const void* g, void* l){
  __builtin_amdgcn_global_load_lds((const __attribute__((address_space(1))) void*)g,
                                   (__attribute__((address_space(3))) void*)l, 16, 0, 0);
}

// ---------------------------------------------------------------------------
// dtype sniffer — separate tiny kernel (R8 lesson: inlining per-thread in the
// convert kernel cost +30us of VMEM issue).
// ---------------------------------------------------------------------------
__global__ void sniff_k(const unsigned short* __restrict__ xu, int* __restrict__ flag)
{
  int t = threadIdx.x;           // 64 threads
  int cnt = 0;
  for (int i = t; i < 1024; i += 64) {
    unsigned short u = xu[i];
    int e = (u >> 7) & 0xFF;
    if (e >= 0x70 && e <= 0x86) cnt++;
  }
  for (int o = 32; o; o >>= 1) cnt += __shfl_down(cnt, o);
  if (t == 0) *flag = (cnt >= 768) ? 0 : 1;
}

// ---------------------------------------------------------------------------
// Fused canonicalizer, x4 vectorized (validated R10/R11) + zero-init of xdbl
// (196608 f32, blocks 0..191 — x_proj split-K accumulates atomically into it).
// d_out zero-init dropped (R13): reduce_out now writes every element.
// ---------------------------------------------------------------------------
struct CvtArgs {
  const void *s0,*s1,*s2,*s3,*s4,*s5,*s6,*s7,*s8,*s9;
  __hip_bfloat16 *xB,*inpB,*xprojB,*dtprojB,*outpB;
  float *cwF,*cbF,*dtbF,*alF,*DF;
  float *xdblZ;
  const int* flag;
};
#define CVT_C1 2097152
#define CVT_C2 6291456
#define CVT_C3 6299648
#define CVT_C4 6301696
#define CVT_C5 6498304
#define CVT_C6 6629376
#define CVT_C7 6631424
#define CVT_C8 6664192
#define CVT_C9 6666240
#define CVT_TOT 8763392
#define CVT_BLOCKS (CVT_TOT/4/256)   // 8558

__device__ __forceinline__ void cvt_read4(const void* s, int j, int fl, float v[4]){
  if (fl) {
    f32x4 t = ((const f32x4*)s)[j>>2];
    v[0]=t.x; v[1]=t.y; v[2]=t.z; v[3]=t.w;
  } else {
    short4v t = *(const short4v*)((const __hip_bfloat16*)s + j);
    v[0]=bfbits2f((unsigned short)t.x); v[1]=bfbits2f((unsigned short)t.y);
    v[2]=bfbits2f((unsigned short)t.z); v[3]=bfbits2f((unsigned short)t.w);
  }
}
__device__ __forceinline__ void cvt_wB(__hip_bfloat16* d, int j, const float v[4]){
  short4v o;
  o.x=(short)f2bfbits(v[0]); o.y=(short)f2bfbits(v[1]);
  o.z=(short)f2bfbits(v[2]); o.w=(short)f2bfbits(v[3]);
  *(short4v*)(d + j) = o;
}
__device__ __forceinline__ void cvt_wF(float* d, int j, const float v[4]){
  f32x4 o = { v[0], v[1], v[2], v[3] };
  *(f32x4*)(d + j) = o;
}

__global__ __launch_bounds__(256)
void convert_all_k(CvtArgs a)
{
  int i4 = blockIdx.x * 256 + threadIdx.x;
  const int fl = *a.flag;

  if (blockIdx.x < 192) {                       // xdbl: 49152 f32x4 exactly
    f32x4 z = {0.f, 0.f, 0.f, 0.f};
    ((f32x4*)a.xdblZ)[i4] = z;
  }

  int i = i4 * 4;
  if (i >= CVT_TOT) return;
  float v[4];
  if (i < CVT_C1)      { cvt_read4(a.s0, i, fl, v);        cvt_wB(a.xB, i, v); }
  else if (i < CVT_C2) { cvt_read4(a.s1, i-CVT_C1, fl, v); cvt_wB(a.inpB, i-CVT_C1, v); }
  else if (i < CVT_C3) { cvt_read4(a.s2, i-CVT_C2, fl, v); cvt_wF(a.cwF, i-CVT_C2, v); }
  else if (i < CVT_C4) { cvt_read4(a.s3, i-CVT_C3, fl, v); cvt_wF(a.cbF, i-CVT_C3, v); }
  else if (i < CVT_C5) { cvt_read4(a.s4, i-CVT_C4, fl, v); cvt_wB(a.xprojB, i-CVT_C4, v); }
  else if (i < CVT_C6) { cvt_read4(a.s5, i-CVT_C5, fl, v); cvt_wB(a.dtprojB, i-CVT_C5, v); }
  else if (i < CVT_C7) { cvt_read4(a.s6, i-CVT_C6, fl, v); cvt_wF(a.dtbF, i-CVT_C6, v); }
  else if (i < CVT_C8) { cvt_read4(a.s7, i-CVT_C7, fl, v); cvt_wF(a.alF, i-CVT_C7, v); }
  else if (i < CVT_C9) { cvt_read4(a.s8, i-CVT_C8, fl, v); cvt_wF(a.DF, i-CVT_C8, v); }
  else                 { cvt_read4(a.s9, i-CVT_C9, fl, v); cvt_wB(a.outpB, i-CVT_C9, v); }
}

// ---------------------------------------------------------------------------
// NT GEMM (validated R8/R9): BK=64, XOR-swizzled LDS staging.
// EPI: 3 = softplus(acc + biasF[col]) -> f32 (delta)
//      4 = in_proj split: col<2048 -> bf16 xi (outH); col>=2048 -> silu -> bf16 outH2
//      5 = split-K atomic into f32 xdbl [row,96] (x_proj)
//      6 = split-K f32 partial -> q[z] (out_proj; R12's atomic epilogue ran
//          at MfmaUtil 6.6% with 32MB RMW traffic — plain stores + reduce)
// ---------------------------------------------------------------------------
template<int EPI>
__global__ __launch_bounds__(256)
void gemm64(const __hip_bfloat16* __restrict__ A,
            const __hip_bfloat16* __restrict__ W,
            int M, int N, int K, int kchunk,
            float* __restrict__ outF,
            __hip_bfloat16* __restrict__ outH,
            __hip_bfloat16* __restrict__ outH2,
            const float* __restrict__ biasF,
            float* __restrict__ q0, float* __restrict__ q1,
            float* __restrict__ q2, float* __restrict__ q3)
{
  __shared__ alignas(16) __hip_bfloat16 As[128*64];   // 16 KB
  __shared__ alignas(16) __hip_bfloat16 Ws[128*64];   // 16 KB
  const int tid  = threadIdx.x;
  const int lane = tid & 63;
  const int wave = tid >> 6;
  const int wm = wave & 1, wn = wave >> 1;
  const int row0 = blockIdx.y * 128;
  const int col0 = blockIdx.x * 128;

  f32x4 acc[4][4] = {};

  int kbeg = 0, kend = K;
  if (EPI == 5 || EPI == 6) { kbeg = blockIdx.z * kchunk; kend = kbeg + kchunk; }

  const int r16 = lane & 15, q = lane >> 4;
  const int sx0 = ((q ^ (r16 & 7)) * 16);

  for (int k0 = kbeg; k0 < kend; k0 += 64) {
#pragma unroll
    for (int j = 0; j < 4; ++j) {             // A tile
      int e = tid + j*256;
      int r = e >> 3, g = e & 7;
      int kc = ((g ^ (r & 7)) << 3);
      gld16(A + (size_t)(row0 + r) * K + k0 + kc, (char*)As + (size_t)e*16);
    }
#pragma unroll
    for (int j = 0; j < 4; ++j) {             // W tile
      int e = tid + j*256;
      int r = e >> 3, g = e & 7;
      int kc = ((g ^ (r & 7)) << 3);
      int rw = col0 + r; if (EPI == 5 && rw > N-1) rw = N-1;
      gld16(W + (size_t)rw * K + k0 + kc, (char*)Ws + (size_t)e*16);
    }
    __syncthreads();

    const char* Ab = (const char*)As + ((wm*64 + r16) * 128);
    const char* Wb = (const char*)Ws + ((wn*64 + r16) * 128);
#pragma unroll
    for (int ksub = 0; ksub < 2; ++ksub) {
      const int sx = sx0 ^ (ksub * 64);
      short8 af[4], wf[4];
#pragma unroll
      for (int i = 0; i < 4; ++i) af[i] = *(const short8*)(Ab + i*16*128 + sx);
#pragma unroll
      for (int i = 0; i < 4; ++i) wf[i] = *(const short8*)(Wb + i*16*128 + sx);
#pragma unroll
      for (int mt = 0; mt < 4; ++mt)
#pragma unroll
        for (int nt = 0; nt < 4; ++nt)
          acc[mt][nt] = __builtin_amdgcn_mfma_f32_16x16x32_bf16(af[mt], wf[nt], acc[mt][nt], 0, 0, 0);
    }
    __syncthreads();
  }

  // C/D layout (verified m89/m91): col = lane&15, row = (lane>>4)*4 + r
  const int mbase = row0 + wm*64 + (q * 4);
  const int nbase = col0 + wn*64 + r16;

  float bv[4];
  if (EPI == 3) {
#pragma unroll
    for (int nt = 0; nt < 4; ++nt) bv[nt] = biasF[nbase + nt*16];
  }
  float* qz = nullptr;
  if (EPI == 6) qz = (blockIdx.z == 0) ? q0 : (blockIdx.z == 1) ? q1
                   : (blockIdx.z == 2) ? q2 : q3;

#pragma unroll
  for (int mt = 0; mt < 4; ++mt) {
#pragma unroll
    for (int nt = 0; nt < 4; ++nt) {
#pragma unroll
      for (int r = 0; r < 4; ++r) {
        int row = mbase + mt*16 + r;
        int col = nbase + nt*16;
        float v = acc[mt][nt][r];
        if (EPI == 3) {
          v += bv[nt];
          float sp = fmaxf(v, 0.0f) + __logf(1.0f + __expf(-fabsf(v)));
          outF[(size_t)row * DINNER + col] = sp;
        } else if (EPI == 4) {
          if (col < DINNER) {
            outH[(size_t)row * DINNER + col] = __float2bfloat16(v);
          } else {
            outH2[(size_t)row * DINNER + (col - DINNER)] = __float2bfloat16(v * sigmoidf_(v));
          }
        } else if (EPI == 5) {
          if (col < 96)
            unsafeAtomicAdd(&outF[(size_t)row * 96 + col], v);
        } else if (EPI == 6) {
          qz[(size_t)row * DMODEL + col] = v;
        }
      }
    }
  }
}

// ---------------------------------------------------------------------------
// out_proj split-K reduce: out = q0+q1+q2+q3, f32x4 vectorized
// ---------------------------------------------------------------------------
__global__ __launch_bounds__(256)
void reduce_out_k(const float* __restrict__ q0, const float* __restrict__ q1,
                  const float* __restrict__ q2, const float* __restrict__ q3,
                  float* __restrict__ out)
{
  int i4 = blockIdx.x * 256 + threadIdx.x;     // ROWS*DMODEL/4 = 524288
  if (i4 >= ROWS*DMODEL/4) return;
  f32x4 a = ((const f32x4*)q0)[i4];
  f32x4 b = ((const f32x4*)q1)[i4];
  f32x4 c = ((const f32x4*)q2)[i4];
  f32x4 d = ((const f32x4*)q3)[i4];
  f32x4 o = { (a.x+b.x)+(c.x+d.x), (a.y+b.y)+(c.y+d.y),
              (a.z+b.z)+(c.z+d.z), (a.w+b.w)+(c.w+d.w) };
  ((f32x4*)out)[i4] = o;
}

// ---------------------------------------------------------------------------
// dt bf16 copy from completed xdbl
// ---------------------------------------------------------------------------
__global__ __launch_bounds__(256)
void dt_cvt_k(const float* __restrict__ xdbl, __hip_bfloat16* __restrict__ dtH)
{
  int i = blockIdx.x * 256 + threadIdx.x;     // ROWS*64 = 131072
  if (i >= ROWS*64) return;
  int row = i >> 6, col = i & 63;
  dtH[i] = __float2bfloat16(xdbl[(size_t)row*96 + col]);
}

// ---------------------------------------------------------------------------
// Depthwise causal conv + bias + SiLU, x4 vectorized (validated R12).
// ---------------------------------------------------------------------------
__global__ __launch_bounds__(256)
void conv_silu_k(const __hip_bfloat16* __restrict__ xi,
                 const float* __restrict__ cw,
                 const float* __restrict__ cb,
                 __hip_bfloat16* __restrict__ xcH)
{
  int idx4 = blockIdx.x * 256 + threadIdx.x;   // ROWS*DINNER/4 threads
  int idx  = idx4 * 4;
  int d  = idx & (DINNER - 1);
  int t  = (idx >> 11) & (SEQ - 1);
  int bt = idx >> 11;

  f32x4 cb4 = *(const f32x4*)&cb[d];
  float a0=cb4.x, a1=cb4.y, a2=cb4.z, a3=cb4.w;
  f32x4 w0 = *(const f32x4*)&cw[(d+0)*4];
  f32x4 w1 = *(const f32x4*)&cw[(d+1)*4];
  f32x4 w2 = *(const f32x4*)&cw[(d+2)*4];
  f32x4 w3 = *(const f32x4*)&cw[(d+3)*4];

#pragma unroll
  for (int i = 0; i < 4; ++i) {
    if (t - 3 + i >= 0) {
      short4v xv = *(const short4v*)(xi + (size_t)(bt - 3 + i) * DINNER + d);
      float x0 = bfbits2f((unsigned short)xv.x);
      float x1 = bfbits2f((unsigned short)xv.y);
      float x2 = bfbits2f((unsigned short)xv.z);
      float x3 = bfbits2f((unsigned short)xv.w);
      float c0 = (i==0)?w0.x:(i==1)?w0.y:(i==2)?w0.z:w0.w;
      float c1 = (i==0)?w1.x:(i==1)?w1.y:(i==2)?w1.z:w1.w;
      float c2 = (i==0)?w2.x:(i==1)?w2.y:(i==2)?w2.z:w2.w;
      float c3 = (i==0)?w3.x:(i==1)?w3.y:(i==2)?w3.z:w3.w;
      a0 += c0*x0; a1 += c1*x1; a2 += c2*x2; a3 += c3*x3;
    }
  }
  float y0 = a0 * sigmoidf_(a0);
  float y1 = a1 * sigmoidf_(a1);
  float y2 = a2 * sigmoidf_(a2);
  float y3 = a3 * sigmoidf_(a3);
  short4v o;
  o.x=(short)f2bfbits(y0); o.y=(short)f2bfbits(y1);
  o.z=(short)f2bfbits(y2); o.w=(short)f2bfbits(y3);
  *(short4v*)(xcH + idx) = o;
}

// ---------------------------------------------------------------------------
// Chunked selective scan (lane layout validated R7, GSTEP=8 validated R11).
// NCHUNK 16->32 (CLEN=32): grid 2048 blocks = 8 blocks/CU — stats/emit were
// latency-bound at VALUBusy ~42% / Occ ~40% with 4 blocks/CU; VGPR 56 and
// LDS 8KB permit 8 blocks/CU.
// ---------------------------------------------------------------------------
#define GSTEP 8

__global__ __launch_bounds__(256)
void stats_k(const float* __restrict__ delta,
             const __hip_bfloat16* __restrict__ xcH,
             const float* __restrict__ xdbl,
             const float* __restrict__ alF,
             float* __restrict__ Hc, float* __restrict__ Sd)
{
  __shared__ alignas(16) float Bs[CLEN*16];     // 2 KB
  const int bid  = blockIdx.x;                  // b*1024 + c*32 + cg
  const int b    = bid >> 10;
  const int c    = (bid >> 5) & (NCHUNK-1);
  const int cg   = bid & 31;
  const int tid  = threadIdx.x;
  const int lane = tid & 63;
  const int wave = tid >> 6;
  const int sub  = lane & 3;
  const int ch   = (cg << 6) + (wave << 4) + (lane >> 2);

  const size_t rb = (size_t)b * SEQ + (size_t)c * CLEN;

  for (int i = tid; i < CLEN*16; i += 256) {
    int t = i >> 4, j = i & 15;
    Bs[i] = xdbl[(rb + t)*96 + 64 + j];
  }
  __syncthreads();

  float negA[4];
#pragma unroll
  for (int j = 0; j < 4; ++j) negA[j] = -__expf(alF[ch*NSTATE + sub*4 + j]);

  const float*          dp = delta + rb * DINNER + ch;
  const __hip_bfloat16* xp = xcH   + rb * DINNER + ch;

  float h0=0.f,h1=0.f,h2=0.f,h3=0.f, sd=0.f;
  float d0[GSTEP], x0[GSTEP], d1[GSTEP], x1[GSTEP];

#define PF1(D_,X_,T0) \
  _Pragma("unroll") \
  for (int u = 0; u < GSTEP; ++u) { \
    D_[u] = dp[(size_t)((T0)+u) * DINNER]; \
    X_[u] = bf2f(xp[(size_t)((T0)+u) * DINNER]); \
  }
#define ST1(D_,X_,T0) \
  _Pragma("unroll") \
  for (int u = 0; u < GSTEP; ++u) { \
    float d_ = D_[u]; \
    sd += d_; \
    float du = d_ * X_[u]; \
    f32x4 B4 = *(const f32x4*)&Bs[((T0)+u)*16 + sub*4]; \
    h0 = __expf(d_*negA[0])*h0 + du*B4.x; \
    h1 = __expf(d_*negA[1])*h1 + du*B4.y; \
    h2 = __expf(d_*negA[2])*h2 + du*B4.z; \
    h3 = __expf(d_*negA[3])*h3 + du*B4.w; \
  }

  PF1(d0, x0, 0)
  for (int t0 = 0; t0 < CLEN; t0 += 2*GSTEP) {
    PF1(d1, x1, t0 + GSTEP)
    ST1(d0, x0, t0)
    if (t0 + 2*GSTEP < CLEN) { PF1(d0, x0, t0 + 2*GSTEP) }
    ST1(d1, x1, t0 + GSTEP)
  }
#undef PF1
#undef ST1

  const size_t bc = (size_t)(b*NCHUNK + c);
  f32x4 hv = { h0, h1, h2, h3 };
  *(f32x4*)&Hc[(bc*DINNER + ch)*NSTATE + sub*4] = hv;
  if (sub == 0) Sd[bc*DINNER + ch] = sd;
}

__global__ __launch_bounds__(256)
void carry_k(const float* __restrict__ Hc, const float* __restrict__ Sd,
             const float* __restrict__ alF, float* __restrict__ hin)
{
  int i = blockIdx.x * 256 + threadIdx.x;       // BATCH*DINNER*NSTATE = 65536
  int n  = i & (NSTATE-1);
  int ch = (i >> 4) & (DINNER-1);
  int b  = i >> 15;
  float negA = -__expf(alF[ch * NSTATE + n]);
  float h = 0.f;
#pragma unroll
  for (int c = 0; c < NCHUNK; ++c) {
    size_t bc = (size_t)(b*NCHUNK + c);
    hin[(bc*DINNER + ch)*NSTATE + n] = h;
    float P = __expf(negA * Sd[bc*DINNER + ch]);
    h = P * h + Hc[(bc*DINNER + ch)*NSTATE + n];
  }
}

__global__ __launch_bounds__(256)
void emit_k(const float* __restrict__ delta,
            const __hip_bfloat16* __restrict__ xcH,
            const float* __restrict__ xdbl,
            const __hip_bfloat16* __restrict__ zsH,
            const float* __restrict__ alF,
            const float* __restrict__ DF,
            const float* __restrict__ hin,
            __hip_bfloat16* __restrict__ yH)
{
  __shared__ alignas(16) float BCs[CLEN*32];    // 4 KB
  const int bid  = blockIdx.x;
  const int b    = bid >> 10;
  const int c    = (bid >> 5) & (NCHUNK-1);
  const int cg   = bid & 31;
  const int tid  = threadIdx.x;
  const int lane = tid & 63;
  const int wave = tid >> 6;
  const int sub  = lane & 3;
  const int ch   = (cg << 6) + (wave << 4) + (lane >> 2);

  const size_t rb = (size_t)b * SEQ + (size_t)c * CLEN;

  for (int i = tid; i < CLEN*32; i += 256) {
    int t = i >> 5, j = i & 31;
    BCs[i] = xdbl[(rb + t)*96 + 64 + j];
  }
  __syncthreads();

  float negA[4];
#pragma unroll
  for (int j = 0; j < 4; ++j) negA[j] = -__expf(alF[ch*NSTATE + sub*4 + j]);
  const float Dch = DF[ch];

  const float*          dp = delta + rb * DINNER + ch;
  const __hip_bfloat16* xp = xcH   + rb * DINNER + ch;
  const __hip_bfloat16* zp = zsH   + rb * DINNER + ch;
  __hip_bfloat16*       yp = yH    + rb * DINNER + ch;

  f32x4 hv = *(const f32x4*)&hin[((size_t)(b*NCHUNK + c)*DINNER + ch)*NSTATE + sub*4];
  float h0=hv.x, h1=hv.y, h2=hv.z, h3=hv.w;

  float d0[GSTEP], x0[GSTEP], z0[GSTEP], d1[GSTEP], x1[GSTEP], z1[GSTEP];

#define PF(D_,X_,Z_,T0) \
  _Pragma("unroll") \
  for (int u = 0; u < GSTEP; ++u) { \
    D_[u] = dp[(size_t)((T0)+u) * DINNER]; \
    X_[u] = bf2f(xp[(size_t)((T0)+u) * DINNER]); \
    Z_[u] = bf2f(zp[(size_t)((T0)+u) * DINNER]); \
  }
#define STEPS(D_,X_,Z_,T0) \
  _Pragma("unroll") \
  for (int u = 0; u < GSTEP; ++u) { \
    float d_ = D_[u]; \
    float du = d_ * X_[u]; \
    f32x4 B4 = *(const f32x4*)&BCs[((T0)+u)*32 + sub*4]; \
    f32x4 C4 = *(const f32x4*)&BCs[((T0)+u)*32 + 16 + sub*4]; \
    h0 = __expf(d_*negA[0])*h0 + du*B4.x; \
    h1 = __expf(d_*negA[1])*h1 + du*B4.y; \
    h2 = __expf(d_*negA[2])*h2 + du*B4.z; \
    h3 = __expf(d_*negA[3])*h3 + du*B4.w; \
    float p = h0*C4.x + h1*C4.y + h2*C4.z + h3*C4.w; \
    p += __shfl_xor(p, 1); \
    p += __shfl_xor(p, 2); \
    if (sub == 0) { \
      float y = (p + X_[u] * Dch) * Z_[u]; \
      yp[(size_t)((T0)+u) * DINNER] = __float2bfloat16(y); \
    } \
  }

  PF(d0, x0, z0, 0)
  for (int t0 = 0; t0 < CLEN; t0 += 2*GSTEP) {
    PF(d1, x1, z1, t0 + GSTEP)
    STEPS(d0, x0, z0, t0)
    if (t0 + 2*GSTEP < CLEN) { PF(d0, x0, z0, t0 + 2*GSTEP) }
    STEPS(d1, x1, z1, t0 + GSTEP)
  }
#undef PF
#undef STEPS
}

// ---------------------------------------------------------------------------
extern "C" void kernel_launch(void* const* d_in, const int* in_sizes, int n_in,
                              void* d_out, int out_size, void* d_ws, size_t ws_size,
                              hipStream_t stream)
{
  float* out = (float*)d_out;   // reference output dtype: float32
  char* ws = (char*)d_ws;
  const size_t MB = 1024*1024;

  // workspace layout (84 MB, liveness-aliased; ws_size = 256 MB)
  int*            flag    = (int*)            (ws);
  float*          cwF     = (float*)          (ws + 1024);
  float*          cbF     = (float*)          (ws + 40*1024);
  float*          dtbF    = (float*)          (ws + 56*1024);
  float*          alF     = (float*)          (ws + 72*1024);
  float*          DF      = (float*)          (ws + 208*1024);
  float*          Sd      = (float*)          (ws + 256*1024);      // 512 KB (NCHUNK=32)
  __hip_bfloat16* xB      = (__hip_bfloat16*) (ws + 1*MB);          // 4 MB  (dead after G1)
  __hip_bfloat16* inpB    = (__hip_bfloat16*) (ws + 5*MB);          // 8 MB  (dead after G1)
  __hip_bfloat16* xiB     = (__hip_bfloat16*) (ws + 13*MB);         // 8 MB  (dead after conv)
  float*          dlt     = (float*)          (ws + 1*MB);          // 16 MB aliases xB/inpB/xiB[:4MB]
  __hip_bfloat16* xprojB  = (__hip_bfloat16*) (ws + 21*MB);
  __hip_bfloat16* dtprojB = (__hip_bfloat16*) (ws + 21*MB + 512*1024);
  __hip_bfloat16* outpB   = (__hip_bfloat16*) (ws + 22*MB);         // 4 MB
  __hip_bfloat16* zsH     = (__hip_bfloat16*) (ws + 26*MB);         // 8 MB (bf16 silu(z))
  __hip_bfloat16* xcH     = (__hip_bfloat16*) (ws + 42*MB);         // 8 MB
  float*          xdbl    = (float*)          (ws + 50*MB);         // 768 KB
  __hip_bfloat16* dtH     = (__hip_bfloat16*) (ws + 51*MB);         // 256 KB
  __hip_bfloat16* yH      = (__hip_bfloat16*) (ws + 52*MB);         // 8 MB (live into out_proj)
  float*          Hc      = (float*)          (ws + 68*MB);         // 8 MB (NCHUNK=32)
  float*          hin     = (float*)          (ws + 76*MB);         // 8 MB -> top 84 MB
  // out_proj f32 partials (8 MB each), regions dead after emit_k:
  float*          q0      = (float*)          (ws + 1*MB);          // dlt (dead)
  float*          q1      = (float*)          (ws + 9*MB);          // dlt hi (dead)
  float*          q2      = (float*)          (ws + 26*MB);         // zsH (dead)
  float*          q3      = (float*)          (ws + 34*MB);         // free

  dim3 blk(256);

  // 0) sniff (1 tiny block) + vectorized canonicalize (+ xdbl zero-init)
  sniff_k<<<1, 64, 0, stream>>>((const unsigned short*)d_in[0], flag);
  CvtArgs ca = { d_in[0], d_in[1], d_in[2], d_in[3], d_in[4],
                 d_in[5], d_in[6], d_in[7], d_in[8], d_in[9],
                 xB, inpB, xprojB, dtprojB, outpB,
                 cwF, cbF, dtbF, alF, DF, xdbl, flag };
  convert_all_k<<<CVT_BLOCKS, blk, 0, stream>>>(ca);

  // 1) in_proj (2048 x 4096 x 1024): split -> xi bf16, silu(z) bf16
  gemm64<4><<<dim3(4096/128, ROWS/128), blk, 0, stream>>>(
      xB, inpB, ROWS, 2*DINNER, DMODEL, 0, nullptr, xiB, zsH, nullptr,
      nullptr, nullptr, nullptr, nullptr);

  // 2) xc = silu(depthwise_conv(xi) + b), x4 vectorized
  conv_silu_k<<<(ROWS*DINNER/4)/256, blk, 0, stream>>>(xiB, cwF, cbF, xcH);

  // 3) x_dbl (2048 x 96 x 2048): 16-way split-K, atomic into zeroed xdbl
  gemm64<5><<<dim3(1, ROWS/128, KSPLIT), blk, 0, stream>>>(
      xcH, xprojB, ROWS, 96, DINNER, DINNER/KSPLIT, xdbl, nullptr, nullptr, nullptr,
      nullptr, nullptr, nullptr, nullptr);
  dt_cvt_k<<<(ROWS*64)/256, blk, 0, stream>>>(xdbl, dtH);

  // 4) delta = softplus(dt @ dt_proj^T + dt_b) (2048 x 2048 x 64): single K-iter
  gemm64<3><<<dim3(DINNER/128, ROWS/128), blk, 0, stream>>>(
      dtH, dtprojB, ROWS, DINNER, DTRANK, 0, dlt, nullptr, nullptr, dtbF,
      nullptr, nullptr, nullptr, nullptr);

  // 5) chunked selective scan (NCHUNK=32) + fused combine -> bf16 yH
  stats_k<<<BATCH*NCHUNK*32, blk, 0, stream>>>(dlt, xcH, xdbl, alF, Hc, Sd);
  carry_k<<<(BATCH*DINNER*NSTATE)/256, blk, 0, stream>>>(Hc, Sd, alF, hin);
  emit_k<<<BATCH*NCHUNK*32, blk, 0, stream>>>(dlt, xcH, xdbl, zsH, alF, DF, hin, yH);

  // 6) out_proj (2048 x 1024 x 2048): split-K=4 f32 partials + vector reduce
  gemm64<6><<<dim3(DMODEL/128, ROWS/128, 4), blk, 0, stream>>>(
      yH, outpB, ROWS, DMODEL, DINNER, DINNER/4, nullptr, nullptr, nullptr, nullptr,
      q0, q1, q2, q3);
  reduce_out_k<<<(ROWS*DMODEL/4)/256, blk, 0, stream>>>(q0, q1, q2, q3, out);
}